// Round 11
// baseline (511.977 us; speedup 1.0000x reference)
//
#include <hip/hip_runtime.h>
#include <math.h>
#include <stdint.h>

#define N_NODES 32768
#define N_EDGES 491520
#define F_IN    11
#define H       64
#define G_GRAPHS 2048
#define NN_PER_G 16
#define R_REACT 1024
#define L_LAYERS 4
#define EIN     129   // 2H+1
#define NIN     139   // 2H+F
#define NPBLK   32    // nodes per k_edge6 block

// preconverted-weight workspace layout (in shorts)
#define WPROJ 0                 // 4 layers x 16384 (16 frags hi @0, lo @8192)
#define WE2   65536             // 4 layers x 8192  (8 frags hi @0, lo @4096)
#define WN1   98304             // 4 layers x 20480 (20 frags hi @0, lo @10240)
#define WN2   180224            // 4 layers x 8192
#define WD1   212992            // 8192
#define WD2   221184            // 8192
#define WEMB  229376            // 4096 (4 frags hi @0, lo @2048)
#define WTOT  233472

typedef __attribute__((ext_vector_type(8))) short short8;
typedef __attribute__((ext_vector_type(4))) float f32x4;

__device__ __forceinline__ float silu_f(float x) {
    return x * __builtin_amdgcn_rcpf(1.0f + __expf(-x));
}
__device__ __forceinline__ void atomAddF(float* p, float v) {
    unsafeAtomicAdd(p, v);
}
__device__ __forceinline__ float bf2f(unsigned short b) {
    union { float f; unsigned u; } v; v.u = ((unsigned)b) << 16;
    return v.f;
}
__device__ __forceinline__ unsigned short f2bf(float x) {   // RNE
    union { float f; unsigned u; } v; v.f = x;
    unsigned r = v.u + 0x7FFFu + ((v.u >> 16) & 1u);
    return (unsigned short)(r >> 16);
}
// RNE split (weights, cold path)
__device__ __forceinline__ void splitbf(float x, unsigned short& hi, unsigned short& lo) {
    hi = f2bf(x);
    lo = f2bf(x - bf2f(hi));
}
// truncation split (hot path; validated absmax 3e-5)
__device__ __forceinline__ void splitbf_t(float x, unsigned short& hi, unsigned short& lo) {
    union { float f; unsigned u; } v; v.f = x;
    hi = (unsigned short)(v.u >> 16);
    union { float f; unsigned u; } w; w.f = x - bf2f(hi);
    lo = (unsigned short)(w.u >> 16);
}

// ---------------- weight fragment pre-conversion (runs once/call) --------
__global__ __launch_bounds__(64) void k_prepw(
        const float* __restrict__ ew1, const float* __restrict__ ew2,
        const float* __restrict__ nw1, const float* __restrict__ nw2,
        const float* __restrict__ dw1, const float* __restrict__ dw2,
        const float* __restrict__ embw,
        short* __restrict__ wsW) {
    const int b = blockIdx.x;
    const int lane = threadIdx.x;
    const int quad = lane >> 4, m16 = lane & 15;
    short8 h8, l8;
    short* base; int fidx, half;

    if (b < 64) {                       // edge_w1 rows 0..127 (proj)
        int l = b >> 4, f = b & 15;
        int nt = f >> 1, kf = f & 1;
#pragma unroll
        for (int j = 0; j < 8; ++j) {
            int row = (nt >= 4 ? 64 : 0) + kf * 32 + quad * 8 + j;
            unsigned short hi, lo;
            splitbf(ew1[l * EIN * H + row * H + (nt & 3) * 16 + m16], hi, lo);
            h8[j] = (short)hi; l8[j] = (short)lo;
        }
        base = wsW + WPROJ + l * 16384; fidx = f; half = 8192;
    } else if (b < 96) {                // edge_w2
        int bb = b - 64; int l = bb >> 3, f = bb & 7;
        int nt = f >> 1, kf = f & 1;
#pragma unroll
        for (int j = 0; j < 8; ++j) {
            int row = kf * 32 + quad * 8 + j;
            unsigned short hi, lo;
            splitbf(ew2[l * H * H + row * H + nt * 16 + m16], hi, lo);
            h8[j] = (short)hi; l8[j] = (short)lo;
        }
        base = wsW + WE2 + l * 8192; fidx = f; half = 4096;
    } else if (b < 176) {               // node_w1 (rows padded to 160)
        int bb = b - 96; int l = bb / 20, f = bb % 20;
        int nt = f / 5, kf = f % 5;
#pragma unroll
        for (int j = 0; j < 8; ++j) {
            int row = kf * 32 + quad * 8 + j;
            float w = (row < NIN) ? nw1[l * NIN * H + row * H + nt * 16 + m16] : 0.0f;
            unsigned short hi, lo; splitbf(w, hi, lo);
            h8[j] = (short)hi; l8[j] = (short)lo;
        }
        base = wsW + WN1 + l * 20480; fidx = f; half = 10240;
    } else if (b < 208) {               // node_w2
        int bb = b - 176; int l = bb >> 3, f = bb & 7;
        int nt = f >> 1, kf = f & 1;
#pragma unroll
        for (int j = 0; j < 8; ++j) {
            int row = kf * 32 + quad * 8 + j;
            unsigned short hi, lo;
            splitbf(nw2[l * H * H + row * H + nt * 16 + m16], hi, lo);
            h8[j] = (short)hi; l8[j] = (short)lo;
        }
        base = wsW + WN2 + l * 8192; fidx = f; half = 4096;
    } else if (b < 216) {               // dec_w1
        int f = b - 208;
        int nt = f >> 1, kf = f & 1;
#pragma unroll
        for (int j = 0; j < 8; ++j) {
            int row = kf * 32 + quad * 8 + j;
            unsigned short hi, lo;
            splitbf(dw1[row * H + nt * 16 + m16], hi, lo);
            h8[j] = (short)hi; l8[j] = (short)lo;
        }
        base = wsW + WD1; fidx = f; half = 4096;
    } else if (b < 224) {               // dec_w2
        int f = b - 216;
        int nt = f >> 1, kf = f & 1;
#pragma unroll
        for (int j = 0; j < 8; ++j) {
            int row = kf * 32 + quad * 8 + j;
            unsigned short hi, lo;
            splitbf(dw2[row * H + nt * 16 + m16], hi, lo);
            h8[j] = (short)hi; l8[j] = (short)lo;
        }
        base = wsW + WD2; fidx = f; half = 4096;
    } else {                            // emb_w (K=32 frag, rows >= F_IN zero)
        int f = b - 224;                // = nt
#pragma unroll
        for (int j = 0; j < 8; ++j) {
            int row = quad * 8 + j;
            float w = (row < F_IN) ? embw[row * H + f * 16 + m16] : 0.0f;
            unsigned short hi, lo; splitbf(w, hi, lo);
            h8[j] = (short)hi; l8[j] = (short)lo;
        }
        base = wsW + WEMB; fidx = f; half = 2048;
    }
    *(short8*)(base + (fidx * 64 + lane) * 8) = h8;
    *(short8*)(base + half + (fidx * 64 + lane) * 8) = l8;
}

// ---------------- CSR build ----------------
__global__ __launch_bounds__(256) void k_hist(
        const int* __restrict__ edges, int* __restrict__ deg) {
    int e = blockIdx.x * 256 + threadIdx.x;
    atomicAdd(&deg[edges[e]], 1);
}

__global__ __launch_bounds__(128) void k_scan_blk(
        const int* __restrict__ deg, int* __restrict__ off,
        int* __restrict__ bsum) {
    __shared__ int sd[128];
    int b = blockIdx.x;
    sd[threadIdx.x] = deg[b * 128 + threadIdx.x];
    __syncthreads();
    if (threadIdx.x == 0) {
        int s = 0;
        for (int i = 0; i < 128; ++i) { int d = sd[i]; sd[i] = s; s += d; }
        bsum[b] = s;
    }
    __syncthreads();
    off[b * 128 + threadIdx.x] = sd[threadIdx.x];
}

__global__ __launch_bounds__(256) void k_scan_top(
        const int* __restrict__ bsum, int* __restrict__ bbase) {
    __shared__ int sb[256];
    sb[threadIdx.x] = bsum[threadIdx.x];
    __syncthreads();
    if (threadIdx.x == 0) {
        int s = 0;
        for (int i = 0; i < 256; ++i) { int d = sb[i]; sb[i] = s; s += d; }
    }
    __syncthreads();
    bbase[threadIdx.x] = sb[threadIdx.x];
}

__global__ __launch_bounds__(256) void k_cursor(
        const int* __restrict__ off, const int* __restrict__ bbase,
        int* __restrict__ nstart, int* __restrict__ cursor) {
    int n = blockIdx.x * 256 + threadIdx.x;
    int ns = off[n] + bbase[n >> 7];
    nstart[n] = ns;
    cursor[n] = ns;
    if (n == 0) nstart[N_NODES] = N_EDGES;
}

// fill: radial fused + PACKED meta (one float4/edge: {pk, rad, mask, 0})
__global__ __launch_bounds__(256) void k_fill(
        const int* __restrict__ edges, const float* __restrict__ posi,
        const float* __restrict__ emask, int* __restrict__ cursor,
        float4* __restrict__ csrQ) {
    int e = blockIdx.x * 256 + threadIdx.x;
    int r = edges[e], c = edges[N_EDGES + e];
    float dx = posi[r * 3 + 0] - posi[c * 3 + 0];
    float dy = posi[r * 3 + 1] - posi[c * 3 + 1];
    float dz = posi[r * 3 + 2] - posi[c * 3 + 2];
    float rad = dx * dx + dy * dy + dz * dz;
    int p = atomicAdd(&cursor[r], 1);
    int pk = c | ((r & (NPBLK - 1)) << 16);  // col | row_local
    csrQ[p] = make_float4(__int_as_float(pk), rad, emask[e], 0.0f);
}

// ---------------- embed + layer-0 projection (fused) ---------------------
__global__ __launch_bounds__(64, 2) void k_embed_proj(
        const float* __restrict__ h0, const short* __restrict__ wEmb,
        const float* __restrict__ emb_b,
        const short* __restrict__ wP, const float* __restrict__ eb1,
        float* __restrict__ h, float* __restrict__ PA, float* __restrict__ PB) {
    const int lane = threadIdx.x;
    const int quad = lane >> 4, m16 = lane & 15;
    const int nb = blockIdx.x * 16;
    __shared__ float tld[16 * 68];

    float a0[8];
    const float* h0p = h0 + (nb + m16) * F_IN;
#pragma unroll
    for (int j = 0; j < 8; ++j) {
        int kk = quad * 8 + j;
        a0[j] = (kk < F_IN) ? h0p[kk] : 0.0f;
    }
    short8 A0h, A0l;
#pragma unroll
    for (int j = 0; j < 8; ++j) {
        unsigned short hi, lo; splitbf_t(a0[j], hi, lo);
        A0h[j] = (short)hi; A0l[j] = (short)lo;
    }
    float ebv[4];
#pragma unroll
    for (int nt = 0; nt < 4; ++nt) ebv[nt] = emb_b[nt * 16 + m16];

#pragma unroll
    for (int nt = 0; nt < 4; ++nt) {
        short8 bh = *(const short8*)(wEmb + (nt * 64 + lane) * 8);
        short8 bl = *(const short8*)(wEmb + 2048 + (nt * 64 + lane) * 8);
        f32x4 a = {0.0f, 0.0f, 0.0f, 0.0f};
        a = __builtin_amdgcn_mfma_f32_16x16x32_bf16(A0h, bh, a, 0, 0, 0);
        a = __builtin_amdgcn_mfma_f32_16x16x32_bf16(A0h, bl, a, 0, 0, 0);
        a = __builtin_amdgcn_mfma_f32_16x16x32_bf16(A0l, bh, a, 0, 0, 0);
#pragma unroll
        for (int r4 = 0; r4 < 4; ++r4) {
            const int node = nb + quad * 4 + r4;
            float hv = a[r4] + ebv[nt];
            h[node * H + nt * 16 + m16] = hv;
            tld[(quad * 4 + r4) * 68 + nt * 16 + m16] = hv;
        }
    }
    __syncthreads();
    float av[16];
    *(float4*)&av[0]  = *(const float4*)&tld[m16 * 68 + quad * 8 + 0];
    *(float4*)&av[4]  = *(const float4*)&tld[m16 * 68 + quad * 8 + 4];
    *(float4*)&av[8]  = *(const float4*)&tld[m16 * 68 + quad * 8 + 32];
    *(float4*)&av[12] = *(const float4*)&tld[m16 * 68 + quad * 8 + 36];
    short8 Ah0, Ah1, Al0, Al1;
#pragma unroll
    for (int j = 0; j < 8; ++j) {
        unsigned short hi, lo;
        splitbf_t(av[j], hi, lo);     Ah0[j] = (short)hi; Al0[j] = (short)lo;
        splitbf_t(av[8 + j], hi, lo); Ah1[j] = (short)hi; Al1[j] = (short)lo;
    }
    float b1v[4];
#pragma unroll
    for (int nt = 0; nt < 4; ++nt) b1v[nt] = eb1[nt * 16 + m16];
#pragma unroll
    for (int nt = 0; nt < 8; ++nt) {
        short8 bh0 = *(const short8*)(wP + ((nt*2+0) * 64 + lane) * 8);
        short8 bh1 = *(const short8*)(wP + ((nt*2+1) * 64 + lane) * 8);
        short8 bl0 = *(const short8*)(wP + 8192 + ((nt*2+0) * 64 + lane) * 8);
        short8 bl1 = *(const short8*)(wP + 8192 + ((nt*2+1) * 64 + lane) * 8);
        f32x4 a = {0.0f, 0.0f, 0.0f, 0.0f};
        a = __builtin_amdgcn_mfma_f32_16x16x32_bf16(Ah0, bh0, a, 0, 0, 0);
        a = __builtin_amdgcn_mfma_f32_16x16x32_bf16(Ah1, bh1, a, 0, 0, 0);
        a = __builtin_amdgcn_mfma_f32_16x16x32_bf16(Ah0, bl0, a, 0, 0, 0);
        a = __builtin_amdgcn_mfma_f32_16x16x32_bf16(Ah1, bl1, a, 0, 0, 0);
        a = __builtin_amdgcn_mfma_f32_16x16x32_bf16(Al0, bh0, a, 0, 0, 0);
        a = __builtin_amdgcn_mfma_f32_16x16x32_bf16(Al1, bh1, a, 0, 0, 0);
#pragma unroll
        for (int r4 = 0; r4 < 4; ++r4) {
            const int node = nb + quad * 4 + r4;
            if (nt < 4)
                PA[node * H + nt * 16 + m16] = a[r4] + b1v[nt];
            else
                PB[node * H + (nt - 4) * 16 + m16] = a[r4];
        }
    }
}

// ------ edge MLP: dual-stream ILP (2 independent tile pipelines/wave) ----
__global__ __launch_bounds__(256, 2) void k_edge6(
        const float* __restrict__ PA, const float* __restrict__ PB,
        const int* __restrict__ nstart, const float4* __restrict__ csrQ,
        const float* __restrict__ W1,   // only row 128 (w1c) used
        const short* __restrict__ wE2, const float* __restrict__ b2,
        float* __restrict__ agg) {
    const int tid = threadIdx.x;
    const int lane = tid & 63, wave = tid >> 6;
    const int quad = lane >> 4, m16 = lane & 15;
    const int n0 = blockIdx.x * NPBLK;

    __shared__ float aggld[NPBLK * 68];
    for (int i = tid; i < NPBLK * 68; i += 256) aggld[i] = 0.0f;

    short8 Bh[8], Bl[8];
#pragma unroll
    for (int f = 0; f < 8; ++f) {
        Bh[f] = *(const short8*)(wE2 + (f * 64 + lane) * 8);
        Bl[f] = *(const short8*)(wE2 + 4096 + (f * 64 + lane) * 8);
    }
    float w1cr[16];
#pragma unroll
    for (int i = 0; i < 16; ++i) {
        int k = (i < 8) ? (quad * 8 + i) : (32 + quad * 8 + (i - 8));
        w1cr[i] = W1[128 * H + k];
    }
    float b2v[4];
#pragma unroll
    for (int nt = 0; nt < 4; ++nt) b2v[nt] = b2[nt * 16 + m16];

    const int start = nstart[n0];
    const int end   = nstart[n0 + NPBLK];
    __syncthreads();

    const int ntiles = (end - start + 15) >> 4;

    // two independent streams: s0 covers tiles {wave, wave+8, ...},
    // s1 covers {wave+4, wave+12, ...}; each stream has R7's 3-stage
    // pipeline (A = data resident, B = meta resident, C = meta in flight).
    int   pkA0 = 0, pkA1 = 0, pkB0 = 0, pkB1 = 0;
    float radA0 = 0.f, radA1 = 0.f, radB0 = 0.f, radB1 = 0.f;
    float av0[16], bv0[16], av1[16], bv1[16];

    int t0 = wave, t1 = wave + 4;
    bool haveA0 = t0 < ntiles, haveA1 = t1 < ntiles;
    if (haveA0) {
        const int idx = start + t0 * 16 + m16;
        const int ss  = min(idx, N_EDGES - 1);
        float4 q = csrQ[ss];
        pkA0 = __float_as_int(q.x); radA0 = q.y;
        const int c = pkA0 & 0xFFFF, rl = pkA0 >> 16;
        const float* par = PA + (n0 + rl) * H + quad * 8;
        const float* pbr = PB + c * H + quad * 8;
        *(float4*)&av0[0]  = *(const float4*)(par + 0);
        *(float4*)&av0[4]  = *(const float4*)(par + 4);
        *(float4*)&av0[8]  = *(const float4*)(par + 32);
        *(float4*)&av0[12] = *(const float4*)(par + 36);
        *(float4*)&bv0[0]  = *(const float4*)(pbr + 0);
        *(float4*)&bv0[4]  = *(const float4*)(pbr + 4);
        *(float4*)&bv0[8]  = *(const float4*)(pbr + 32);
        *(float4*)&bv0[12] = *(const float4*)(pbr + 36);
    }
    if (haveA1) {
        const int idx = start + t1 * 16 + m16;
        const int ss  = min(idx, N_EDGES - 1);
        float4 q = csrQ[ss];
        pkA1 = __float_as_int(q.x); radA1 = q.y;
        const int c = pkA1 & 0xFFFF, rl = pkA1 >> 16;
        const float* par = PA + (n0 + rl) * H + quad * 8;
        const float* pbr = PB + c * H + quad * 8;
        *(float4*)&av1[0]  = *(const float4*)(par + 0);
        *(float4*)&av1[4]  = *(const float4*)(par + 4);
        *(float4*)&av1[8]  = *(const float4*)(par + 32);
        *(float4*)&av1[12] = *(const float4*)(par + 36);
        *(float4*)&bv1[0]  = *(const float4*)(pbr + 0);
        *(float4*)&bv1[4]  = *(const float4*)(pbr + 4);
        *(float4*)&bv1[8]  = *(const float4*)(pbr + 32);
        *(float4*)&bv1[12] = *(const float4*)(pbr + 36);
    }
    int u0 = t0 + 8, u1 = t1 + 8;
    bool haveB0 = u0 < ntiles, haveB1 = u1 < ntiles;
    if (haveB0) {
        const int idx = start + u0 * 16 + m16;
        float4 q = csrQ[min(idx, N_EDGES - 1)];
        pkB0 = __float_as_int(q.x); radB0 = q.y;
    }
    if (haveB1) {
        const int idx = start + u1 * 16 + m16;
        float4 q = csrQ[min(idx, N_EDGES - 1)];
        pkB1 = __float_as_int(q.x); radB1 = q.y;
    }

    while (haveA0 || haveA1) {
        // 1. gather B data for both streams (meta resident)
        float bvB0[16], bvB1[16];
        if (haveB0) {
            const int c = pkB0 & 0xFFFF;
            const float* pbr = PB + c * H + quad * 8;
            *(float4*)&bvB0[0]  = *(const float4*)(pbr + 0);
            *(float4*)&bvB0[4]  = *(const float4*)(pbr + 4);
            *(float4*)&bvB0[8]  = *(const float4*)(pbr + 32);
            *(float4*)&bvB0[12] = *(const float4*)(pbr + 36);
        }
        if (haveB1) {
            const int c = pkB1 & 0xFFFF;
            const float* pbr = PB + c * H + quad * 8;
            *(float4*)&bvB1[0]  = *(const float4*)(pbr + 0);
            *(float4*)&bvB1[4]  = *(const float4*)(pbr + 4);
            *(float4*)&bvB1[8]  = *(const float4*)(pbr + 32);
            *(float4*)&bvB1[12] = *(const float4*)(pbr + 36);
        }
        // 2. issue meta loads for C (both streams)
        const int v0 = u0 + 8, v1 = u1 + 8;
        const bool haveC0 = v0 < ntiles, haveC1 = v1 < ntiles;
        int pkC0 = 0, pkC1 = 0; float radC0 = 0.f, radC1 = 0.f;
        if (haveC0) {
            const int idx = start + v0 * 16 + m16;
            float4 q = csrQ[min(idx, N_EDGES - 1)];
            pkC0 = __float_as_int(q.x); radC0 = q.y;
        }
        if (haveC1) {
            const int idx = start + v1 * 16 + m16;
            float4 q = csrQ[min(idx, N_EDGES - 1)];
            pkC1 = __float_as_int(q.x); radC1 = q.y;
        }
        // 3. per-quad meta for both A tiles (packed, L1-warm)
        int rlq0[4] = {0,0,0,0}, rlq1[4] = {0,0,0,0};
        float mkq0[4] = {0,0,0,0}, mkq1[4] = {0,0,0,0};
        if (haveA0) {
            const int sb = start + t0 * 16 + quad * 4;
#pragma unroll
            for (int r4 = 0; r4 < 4; ++r4) {
                int s = sb + r4, s2 = min(s, N_EDGES - 1);
                float4 q = csrQ[s2];
                rlq0[r4] = __float_as_int(q.x) >> 16;
                mkq0[r4] = (s < end) ? q.z : 0.0f;
            }
        }
        if (haveA1) {
            const int sb = start + t1 * 16 + quad * 4;
#pragma unroll
            for (int r4 = 0; r4 < 4; ++r4) {
                int s = sb + r4, s2 = min(s, N_EDGES - 1);
                float4 q = csrQ[s2];
                rlq1[r4] = __float_as_int(q.x) >> 16;
                mkq1[r4] = (s < end) ? q.z : 0.0f;
            }
        }

        // 4a. compute + epilogue stream 0
        if (haveA0) {
            short8 Ah0, Ah1, Al0, Al1;
#pragma unroll
            for (int i = 0; i < 8; ++i) {
                unsigned short hi, lo;
                splitbf_t(silu_f(av0[i] + bv0[i] + radA0 * w1cr[i]), hi, lo);
                Ah0[i] = (short)hi; Al0[i] = (short)lo;
                splitbf_t(silu_f(av0[8+i] + bv0[8+i] + radA0 * w1cr[8+i]), hi, lo);
                Ah1[i] = (short)hi; Al1[i] = (short)lo;
            }
#pragma unroll
            for (int nt = 0; nt < 4; ++nt) {
                f32x4 a = {0.0f, 0.0f, 0.0f, 0.0f};
                a = __builtin_amdgcn_mfma_f32_16x16x32_bf16(Ah0, Bh[nt*2+0], a, 0, 0, 0);
                a = __builtin_amdgcn_mfma_f32_16x16x32_bf16(Ah1, Bh[nt*2+1], a, 0, 0, 0);
                a = __builtin_amdgcn_mfma_f32_16x16x32_bf16(Ah0, Bl[nt*2+0], a, 0, 0, 0);
                a = __builtin_amdgcn_mfma_f32_16x16x32_bf16(Ah1, Bl[nt*2+1], a, 0, 0, 0);
                a = __builtin_amdgcn_mfma_f32_16x16x32_bf16(Al0, Bh[nt*2+0], a, 0, 0, 0);
                a = __builtin_amdgcn_mfma_f32_16x16x32_bf16(Al1, Bh[nt*2+1], a, 0, 0, 0);
                float oo[4];
#pragma unroll
                for (int r4 = 0; r4 < 4; ++r4)
                    oo[r4] = silu_f(a[r4] + b2v[nt]) * mkq0[r4];
                int cur = rlq0[0]; float s = oo[0];
#pragma unroll
                for (int r4 = 1; r4 < 4; ++r4) {
                    if (rlq0[r4] == cur) { s += oo[r4]; }
                    else {
                        atomicAdd(&aggld[cur * 68 + nt * 16 + m16], s);
                        cur = rlq0[r4]; s = oo[r4];
                    }
                }
                atomicAdd(&aggld[cur * 68 + nt * 16 + m16], s);
            }
        }
        // 4b. compute + epilogue stream 1
        if (haveA1) {
            short8 Ah0, Ah1, Al0, Al1;
#pragma unroll
            for (int i = 0; i < 8; ++i) {
                unsigned short hi, lo;
                splitbf_t(silu_f(av1[i] + bv1[i] + radA1 * w1cr[i]), hi, lo);
                Ah0[i] = (short)hi; Al0[i] = (short)lo;
                splitbf_t(silu_f(av1[8+i] + bv1[8+i] + radA1 * w1cr[8+i]), hi, lo);
                Ah1[i] = (short)hi; Al1[i] = (short)lo;
            }
#pragma unroll
            for (int nt = 0; nt < 4; ++nt) {
                f32x4 a = {0.0f, 0.0f, 0.0f, 0.0f};
                a = __builtin_amdgcn_mfma_f32_16x16x32_bf16(Ah0, Bh[nt*2+0], a, 0, 0, 0);
                a = __builtin_amdgcn_mfma_f32_16x16x32_bf16(Ah1, Bh[nt*2+1], a, 0, 0, 0);
                a = __builtin_amdgcn_mfma_f32_16x16x32_bf16(Ah0, Bl[nt*2+0], a, 0, 0, 0);
                a = __builtin_amdgcn_mfma_f32_16x16x32_bf16(Ah1, Bl[nt*2+1], a, 0, 0, 0);
                a = __builtin_amdgcn_mfma_f32_16x16x32_bf16(Al0, Bh[nt*2+0], a, 0, 0, 0);
                a = __builtin_amdgcn_mfma_f32_16x16x32_bf16(Al1, Bh[nt*2+1], a, 0, 0, 0);
                float oo[4];
#pragma unroll
                for (int r4 = 0; r4 < 4; ++r4)
                    oo[r4] = silu_f(a[r4] + b2v[nt]) * mkq1[r4];
                int cur = rlq1[0]; float s = oo[0];
#pragma unroll
                for (int r4 = 1; r4 < 4; ++r4) {
                    if (rlq1[r4] == cur) { s += oo[r4]; }
                    else {
                        atomicAdd(&aggld[cur * 68 + nt * 16 + m16], s);
                        cur = rlq1[r4]; s = oo[r4];
                    }
                }
                atomicAdd(&aggld[cur * 68 + nt * 16 + m16], s);
            }
        }

        // 5. shift both pipelines (av reload is L1-hot; late is fine)
        if (haveB0) {
            const int rl = pkB0 >> 16;
            const float* par = PA + (n0 + rl) * H + quad * 8;
            *(float4*)&av0[0]  = *(const float4*)(par + 0);
            *(float4*)&av0[4]  = *(const float4*)(par + 4);
            *(float4*)&av0[8]  = *(const float4*)(par + 32);
            *(float4*)&av0[12] = *(const float4*)(par + 36);
#pragma unroll
            for (int i = 0; i < 16; ++i) bv0[i] = bvB0[i];
            pkA0 = pkB0; radA0 = radB0;
        }
        if (haveB1) {
            const int rl = pkB1 >> 16;
            const float* par = PA + (n0 + rl) * H + quad * 8;
            *(float4*)&av1[0]  = *(const float4*)(par + 0);
            *(float4*)&av1[4]  = *(const float4*)(par + 4);
            *(float4*)&av1[8]  = *(const float4*)(par + 32);
            *(float4*)&av1[12] = *(const float4*)(par + 36);
#pragma unroll
            for (int i = 0; i < 16; ++i) bv1[i] = bvB1[i];
            pkA1 = pkB1; radA1 = radB1;
        }
        haveA0 = haveB0; haveA1 = haveB1;
        pkB0 = pkC0; radB0 = radC0; haveB0 = haveC0;
        pkB1 = pkC1; radB1 = radC1; haveB1 = haveC1;
        t0 = u0; u0 = v0; t1 = u1; u1 = v1;
    }

    __syncthreads();
#pragma unroll
    for (int i = tid; i < NPBLK * 16; i += 256) {
        int n = i >> 4, cb = (i & 15) << 2;
        *(float4*)&agg[(n0 + n) * H + cb] = *(const float4*)&aggld[n * 68 + cb];
    }
}

// ---------------- node MLP + next-layer projection (fused) ---------------
__global__ __launch_bounds__(64, 2) void k_node_proj(
        float* __restrict__ h, const float* __restrict__ agg,
        const float* __restrict__ h0,
        const short* __restrict__ wN1, const float* __restrict__ b1,
        const short* __restrict__ wN2, const float* __restrict__ b2,
        const short* __restrict__ wPn, const float* __restrict__ eb1n,
        float* __restrict__ PA, float* __restrict__ PB) {
    const int lane = threadIdx.x;
    const int quad = lane >> 4, m16 = lane & 15;
    const int nb = blockIdx.x * 16;

    float b1v[4], b2v[4];
#pragma unroll
    for (int nt = 0; nt < 4; ++nt) {
        b1v[nt] = b1[nt * 16 + m16];
        b2v[nt] = b2[nt * 16 + m16];
    }
    __shared__ float tld[16 * 68];

    // ---- node MLP layer 1 ----
    float a1[5][8];
    const float* hp = h + (nb + m16) * H + quad * 8;
    const float* ap = agg + (nb + m16) * H + quad * 8;
    *(float4*)&a1[0][0] = *(const float4*)(hp + 0);
    *(float4*)&a1[0][4] = *(const float4*)(hp + 4);
    *(float4*)&a1[1][0] = *(const float4*)(hp + 32);
    *(float4*)&a1[1][4] = *(const float4*)(hp + 36);
    *(float4*)&a1[2][0] = *(const float4*)(ap + 0);
    *(float4*)&a1[2][4] = *(const float4*)(ap + 4);
    *(float4*)&a1[3][0] = *(const float4*)(ap + 32);
    *(float4*)&a1[3][4] = *(const float4*)(ap + 36);
    const float* h0p = h0 + (nb + m16) * F_IN;
#pragma unroll
    for (int j = 0; j < 8; ++j) {
        int kk = quad * 8 + j;
        a1[4][j] = (kk < F_IN) ? h0p[kk] : 0.0f;
    }
    short8 A1h[5], A1l[5];
#pragma unroll
    for (int kf = 0; kf < 5; ++kf) {
        short8 ah, al;
#pragma unroll
        for (int j = 0; j < 8; ++j) {
            unsigned short hi, lo; splitbf_t(a1[kf][j], hi, lo);
            ah[j] = (short)hi; al[j] = (short)lo;
        }
        A1h[kf] = ah; A1l[kf] = al;
    }
#pragma unroll
    for (int nt = 0; nt < 4; ++nt) {
        short8 bh[5], bl[5];
#pragma unroll
        for (int kf = 0; kf < 5; ++kf) {
            bh[kf] = *(const short8*)(wN1 + ((nt*5+kf) * 64 + lane) * 8);
            bl[kf] = *(const short8*)(wN1 + 10240 + ((nt*5+kf) * 64 + lane) * 8);
        }
        f32x4 a = {0.0f, 0.0f, 0.0f, 0.0f};
#pragma unroll
        for (int kf = 0; kf < 5; ++kf)
            a = __builtin_amdgcn_mfma_f32_16x16x32_bf16(A1h[kf], bh[kf], a, 0, 0, 0);
#pragma unroll
        for (int kf = 0; kf < 5; ++kf)
            a = __builtin_amdgcn_mfma_f32_16x16x32_bf16(A1h[kf], bl[kf], a, 0, 0, 0);
#pragma unroll
        for (int kf = 0; kf < 5; ++kf)
            a = __builtin_amdgcn_mfma_f32_16x16x32_bf16(A1l[kf], bh[kf], a, 0, 0, 0);
#pragma unroll
        for (int r4 = 0; r4 < 4; ++r4)
            tld[(quad * 4 + r4) * 68 + nt * 16 + m16] = silu_f(a[r4] + b1v[nt]);
    }
    __syncthreads();
    // ---- node MLP layer 2 ----
    float a2[16];
    *(float4*)&a2[0]  = *(const float4*)&tld[m16 * 68 + quad * 8 + 0];
    *(float4*)&a2[4]  = *(const float4*)&tld[m16 * 68 + quad * 8 + 4];
    *(float4*)&a2[8]  = *(const float4*)&tld[m16 * 68 + quad * 8 + 32];
    *(float4*)&a2[12] = *(const float4*)&tld[m16 * 68 + quad * 8 + 36];
    short8 A2h0, A2h1, A2l0, A2l1;
#pragma unroll
    for (int j = 0; j < 8; ++j) {
        unsigned short hi, lo;
        splitbf_t(a2[j], hi, lo);     A2h0[j] = (short)hi; A2l0[j] = (short)lo;
        splitbf_t(a2[8+j], hi, lo);   A2h1[j] = (short)hi; A2l1[j] = (short)lo;
    }
    __syncthreads();   // a2 reads complete before tld overwritten
#pragma unroll
    for (int nt = 0; nt < 4; ++nt) {
        short8 bh0 = *(const short8*)(wN2 + ((nt*2+0) * 64 + lane) * 8);
        short8 bh1 = *(const short8*)(wN2 + ((nt*2+1) * 64 + lane) * 8);
        short8 bl0 = *(const short8*)(wN2 + 4096 + ((nt*2+0) * 64 + lane) * 8);
        short8 bl1 = *(const short8*)(wN2 + 4096 + ((nt*2+1) * 64 + lane) * 8);
        f32x4 a = {0.0f, 0.0f, 0.0f, 0.0f};
        a = __builtin_amdgcn_mfma_f32_16x16x32_bf16(A2h0, bh0, a, 0, 0, 0);
        a = __builtin_amdgcn_mfma_f32_16x16x32_bf16(A2h1, bh1, a, 0, 0, 0);
        a = __builtin_amdgcn_mfma_f32_16x16x32_bf16(A2h0, bl0, a, 0, 0, 0);
        a = __builtin_amdgcn_mfma_f32_16x16x32_bf16(A2h1, bl1, a, 0, 0, 0);
        a = __builtin_amdgcn_mfma_f32_16x16x32_bf16(A2l0, bh0, a, 0, 0, 0);
        a = __builtin_amdgcn_mfma_f32_16x16x32_bf16(A2l1, bh1, a, 0, 0, 0);
#pragma unroll
        for (int r4 = 0; r4 < 4; ++r4) {
            const int node = nb + quad * 4 + r4;
            float hv = a[r4] + b2v[nt];
            h[node * H + nt * 16 + m16] = hv;
            tld[(quad * 4 + r4) * 68 + nt * 16 + m16] = hv;
        }
    }
    __syncthreads();
    // ---- projection for next layer ----
    float av[16];
    *(float4*)&av[0]  = *(const float4*)&tld[m16 * 68 + quad * 8 + 0];
    *(float4*)&av[4]  = *(const float4*)&tld[m16 * 68 + quad * 8 + 4];
    *(float4*)&av[8]  = *(const float4*)&tld[m16 * 68 + quad * 8 + 32];
    *(float4*)&av[12] = *(const float4*)&tld[m16 * 68 + quad * 8 + 36];
    short8 Ph0, Ph1, Pl0, Pl1;
#pragma unroll
    for (int j = 0; j < 8; ++j) {
        unsigned short hi, lo;
        splitbf_t(av[j], hi, lo);     Ph0[j] = (short)hi; Pl0[j] = (short)lo;
        splitbf_t(av[8+j], hi, lo);   Ph1[j] = (short)hi; Pl1[j] = (short)lo;
    }
    float b1ev[4];
#pragma unroll
    for (int nt = 0; nt < 4; ++nt) b1ev[nt] = eb1n[nt * 16 + m16];
#pragma unroll
    for (int nt = 0; nt < 8; ++nt) {
        short8 bh0 = *(const short8*)(wPn + ((nt*2+0) * 64 + lane) * 8);
        short8 bh1 = *(const short8*)(wPn + ((nt*2+1) * 64 + lane) * 8);
        short8 bl0 = *(const short8*)(wPn + 8192 + ((nt*2+0) * 64 + lane) * 8);
        short8 bl1 = *(const short8*)(wPn + 8192 + ((nt*2+1) * 64 + lane) * 8);
        f32x4 a = {0.0f, 0.0f, 0.0f, 0.0f};
        a = __builtin_amdgcn_mfma_f32_16x16x32_bf16(Ph0, bh0, a, 0, 0, 0);
        a = __builtin_amdgcn_mfma_f32_16x16x32_bf16(Ph1, bh1, a, 0, 0, 0);
        a = __builtin_amdgcn_mfma_f32_16x16x32_bf16(Ph0, bl0, a, 0, 0, 0);
        a = __builtin_amdgcn_mfma_f32_16x16x32_bf16(Ph1, bl1, a, 0, 0, 0);
        a = __builtin_amdgcn_mfma_f32_16x16x32_bf16(Pl0, bh0, a, 0, 0, 0);
        a = __builtin_amdgcn_mfma_f32_16x16x32_bf16(Pl1, bh1, a, 0, 0, 0);
#pragma unroll
        for (int r4 = 0; r4 < 4; ++r4) {
            const int node = nb + quad * 4 + r4;
            if (nt < 4)
                PA[node * H + nt * 16 + m16] = a[r4] + b1ev[nt];
            else
                PB[node * H + (nt - 4) * 16 + m16] = a[r4];
        }
    }
}

// ------- layer-3 node MLP + node decoder + pool + graph dec + reaction ---
__global__ __launch_bounds__(64, 2) void k_node_dec_graph(
        const float* __restrict__ h, const float* __restrict__ agg,
        const float* __restrict__ h0,
        const short* __restrict__ wN1, const float* __restrict__ b1,
        const short* __restrict__ wN2, const float* __restrict__ b2,
        const short* __restrict__ wD1, const float* __restrict__ db1,
        const short* __restrict__ wD2, const float* __restrict__ db2,
        const float* __restrict__ nmask,
        const float* __restrict__ gW1, const float* __restrict__ gb1,
        const float* __restrict__ gW2, const float* __restrict__ gb2,
        const int* __restrict__ rid, const float* __restrict__ rsign,
        float* __restrict__ pred) {
    const int lane = threadIdx.x;
    const int quad = lane >> 4, m16 = lane & 15;
    const int nb = blockIdx.x * 16;

    float b1v[4], b2v[4], db1v[4], db2v[4];
#pragma unroll
    for (int nt = 0; nt < 4; ++nt) {
        b1v[nt]  = b1[nt * 16 + m16];
        b2v[nt]  = b2[nt * 16 + m16];
        db1v[nt] = db1[nt * 16 + m16];
        db2v[nt] = db2[nt * 16 + m16];
    }
    float nm[4];
#pragma unroll
    for (int r4 = 0; r4 < 4; ++r4) nm[r4] = nmask[nb + quad * 4 + r4];

    __shared__ float tld[16 * 68];
    __shared__ __align__(16) float hgs[64];

    // ---- node MLP layer 1 ----
    float a1[5][8];
    const float* hp = h + (nb + m16) * H + quad * 8;
    const float* ap = agg + (nb + m16) * H + quad * 8;
    *(float4*)&a1[0][0] = *(const float4*)(hp + 0);
    *(float4*)&a1[0][4] = *(const float4*)(hp + 4);
    *(float4*)&a1[1][0] = *(const float4*)(hp + 32);
    *(float4*)&a1[1][4] = *(const float4*)(hp + 36);
    *(float4*)&a1[2][0] = *(const float4*)(ap + 0);
    *(float4*)&a1[2][4] = *(const float4*)(ap + 4);
    *(float4*)&a1[3][0] = *(const float4*)(ap + 32);
    *(float4*)&a1[3][4] = *(const float4*)(ap + 36);
    const float* h0p = h0 + (nb + m16) * F_IN;
#pragma unroll
    for (int j = 0; j < 8; ++j) {
        int kk = quad * 8 + j;
        a1[4][j] = (kk < F_IN) ? h0p[kk] : 0.0f;
    }
    short8 A1h[5], A1l[5];
#pragma unroll
    for (int kf = 0; kf < 5; ++kf) {
        short8 ah, al;
#pragma unroll
        for (int j = 0; j < 8; ++j) {
            unsigned short hi, lo; splitbf_t(a1[kf][j], hi, lo);
            ah[j] = (short)hi; al[j] = (short)lo;
        }
        A1h[kf] = ah; A1l[kf] = al;
    }
#pragma unroll
    for (int nt = 0; nt < 4; ++nt) {
        short8 bh[5], bl[5];
#pragma unroll
        for (int kf = 0; kf < 5; ++kf) {
            bh[kf] = *(const short8*)(wN1 + ((nt*5+kf) * 64 + lane) * 8);
            bl[kf] = *(const short8*)(wN1 + 10240 + ((nt*5+kf) * 64 + lane) * 8);
        }
        f32x4 a = {0.0f, 0.0f, 0.0f, 0.0f};
#pragma unroll
        for (int kf = 0; kf < 5; ++kf)
            a = __builtin_amdgcn_mfma_f32_16x16x32_bf16(A1h[kf], bh[kf], a, 0, 0, 0);
#pragma unroll
        for (int kf = 0; kf < 5; ++kf)
            a = __builtin_amdgcn_mfma_f32_16x16x32_bf16(A1h[kf], bl[kf], a, 0, 0, 0);
#pragma unroll
        for (int kf = 0; kf < 5; ++kf)
            a = __builtin_amdgcn_mfma_f32_16x16x32_bf16(A1l[kf], bh[kf], a, 0, 0, 0);
#pragma unroll
        for (int r4 = 0; r4 < 4; ++r4)
            tld[(quad * 4 + r4) * 68 + nt * 16 + m16] = silu_f(a[r4] + b1v[nt]);
    }
    __syncthreads();
    // ---- node MLP layer 2 (h_new stays in LDS) ----
    float a2[16];
    *(float4*)&a2[0]  = *(const float4*)&tld[m16 * 68 + quad * 8 + 0];
    *(float4*)&a2[4]  = *(const float4*)&tld[m16 * 68 + quad * 8 + 4];
    *(float4*)&a2[8]  = *(const float4*)&tld[m16 * 68 + quad * 8 + 32];
    *(float4*)&a2[12] = *(const float4*)&tld[m16 * 68 + quad * 8 + 36];
    short8 A2h0, A2h1, A2l0, A2l1;
#pragma unroll
    for (int j = 0; j < 8; ++j) {
        unsigned short hi, lo;
        splitbf_t(a2[j], hi, lo);     A2h0[j] = (short)hi; A2l0[j] = (short)lo;
        splitbf_t(a2[8+j], hi, lo);   A2h1[j] = (short)hi; A2l1[j] = (short)lo;
    }
    __syncthreads();
#pragma unroll
    for (int nt = 0; nt < 4; ++nt) {
        short8 bh0 = *(const short8*)(wN2 + ((nt*2+0) * 64 + lane) * 8);
        short8 bh1 = *(const short8*)(wN2 + ((nt*2+1) * 64 + lane) * 8);
        short8 bl0 = *(const short8*)(wN2 + 4096 + ((nt*2+0) * 64 + lane) * 8);
        short8 bl1 = *(const short8*)(wN2 + 4096 + ((nt*2+1) * 64 + lane) * 8);
        f32x4 a = {0.0f, 0.0f, 0.0f, 0.0f};
        a = __builtin_amdgcn_mfma_f32_16x16x32_bf16(A2h0, bh0, a, 0, 0, 0);
        a = __builtin_amdgcn_mfma_f32_16x16x32_bf16(A2h1, bh1, a, 0, 0, 0);
        a = __builtin_amdgcn_mfma_f32_16x16x32_bf16(A2h0, bl0, a, 0, 0, 0);
        a = __builtin_amdgcn_mfma_f32_16x16x32_bf16(A2h1, bl1, a, 0, 0, 0);
        a = __builtin_amdgcn_mfma_f32_16x16x32_bf16(A2l0, bh0, a, 0, 0, 0);
        a = __builtin_amdgcn_mfma_f32_16x16x32_bf16(A2l1, bh1, a, 0, 0, 0);
#pragma unroll
        for (int r4 = 0; r4 < 4; ++r4)
            tld[(quad * 4 + r4) * 68 + nt * 16 + m16] = a[r4] + b2v[nt];
    }
    __syncthreads();
    // ---- decoder layer 1 ----
    float av[16];
    *(float4*)&av[0]  = *(const float4*)&tld[m16 * 68 + quad * 8 + 0];
    *(float4*)&av[4]  = *(const float4*)&tld[m16 * 68 + quad * 8 + 4];
    *(float4*)&av[8]  = *(const float4*)&tld[m16 * 68 + quad * 8 + 32];
    *(float4*)&av[12] = *(const float4*)&tld[m16 * 68 + quad * 8 + 36];
    short8 Dh0, Dh1, Dl0, Dl1;
#pragma unroll
    for (int j = 0; j < 8; ++j) {
        unsigned short hi, lo;
        splitbf_t(av[j], hi, lo);     Dh0[j] = (short)hi; Dl0[j] = (short)lo;
        splitbf_t(av[8+j], hi, lo);   Dh1[j] = (short)hi; Dl1[j] = (short)lo;
    }
    __syncthreads();
#pragma unroll
    for (int nt = 0; nt < 4; ++nt) {
        short8 bh0 = *(const short8*)(wD1 + ((nt*2+0) * 64 + lane) * 8);
        short8 bh1 = *(const short8*)(wD1 + ((nt*2+1) * 64 + lane) * 8);
        short8 bl0 = *(const short8*)(wD1 + 4096 + ((nt*2+0) * 64 + lane) * 8);
        short8 bl1 = *(const short8*)(wD1 + 4096 + ((nt*2+1) * 64 + lane) * 8);
        f32x4 a = {0.0f, 0.0f, 0.0f, 0.0f};
        a = __builtin_amdgcn_mfma_f32_16x16x32_bf16(Dh0, bh0, a, 0, 0, 0);
        a = __builtin_amdgcn_mfma_f32_16x16x32_bf16(Dh1, bh1, a, 0, 0, 0);
        a = __builtin_amdgcn_mfma_f32_16x16x32_bf16(Dh0, bl0, a, 0, 0, 0);
        a = __builtin_amdgcn_mfma_f32_16x16x32_bf16(Dh1, bl1, a, 0, 0, 0);
        a = __builtin_amdgcn_mfma_f32_16x16x32_bf16(Dl0, bh0, a, 0, 0, 0);
        a = __builtin_amdgcn_mfma_f32_16x16x32_bf16(Dl1, bh1, a, 0, 0, 0);
#pragma unroll
        for (int r4 = 0; r4 < 4; ++r4)
            tld[(quad * 4 + r4) * 68 + nt * 16 + m16] = silu_f(a[r4] + db1v[nt]);
    }
    __syncthreads();
    // ---- decoder layer 2 + mask + pool ----
    float a3[16];
    *(float4*)&a3[0]  = *(const float4*)&tld[m16 * 68 + quad * 8 + 0];
    *(float4*)&a3[4]  = *(const float4*)&tld[m16 * 68 + quad * 8 + 4];
    *(float4*)&a3[8]  = *(const float4*)&tld[m16 * 68 + quad * 8 + 32];
    *(float4*)&a3[12] = *(const float4*)&tld[m16 * 68 + quad * 8 + 36];
    short8 Eh0, Eh1, El0, El1;
#pragma unroll
    for (int j = 0; j < 8; ++j) {
        unsigned short hi, lo;
        splitbf_t(a3[j], hi, lo);     Eh0[j] = (short)hi; El0[j] = (short)lo;
        splitbf_t(a3[8+j], hi, lo);   Eh1[j] = (short)hi; El1[j] = (short)lo;
    }
#pragma unroll
    for (int nt = 0; nt < 4; ++nt) {
        short8 bh0 = *(const short8*)(wD2 + ((nt*2+0) * 64 + lane) * 8);
        short8 bh1 = *(const short8*)(wD2 + ((nt*2+1) * 64 + lane) * 8);
        short8 bl0 = *(const short8*)(wD2 + 4096 + ((nt*2+0) * 64 + lane) * 8);
        short8 bl1 = *(const short8*)(wD2 + 4096 + ((nt*2+1) * 64 + lane) * 8);
        f32x4 a = {0.0f, 0.0f, 0.0f, 0.0f};
        a = __builtin_amdgcn_mfma_f32_16x16x32_bf16(Eh0, bh0, a, 0, 0, 0);
        a = __builtin_amdgcn_mfma_f32_16x16x32_bf16(Eh1, bh1, a, 0, 0, 0);
        a = __builtin_amdgcn_mfma_f32_16x16x32_bf16(Eh0, bl0, a, 0, 0, 0);
        a = __builtin_amdgcn_mfma_f32_16x16x32_bf16(Eh1, bl1, a, 0, 0, 0);
        a = __builtin_amdgcn_mfma_f32_16x16x32_bf16(El0, bh0, a, 0, 0, 0);
        a = __builtin_amdgcn_mfma_f32_16x16x32_bf16(El1, bh1, a, 0, 0, 0);
        float s = 0.0f;
#pragma unroll
        for (int r4 = 0; r4 < 4; ++r4)
            s += (a[r4] + db2v[nt]) * nm[r4];
        s += __shfl_xor(s, 16);
        s += __shfl_xor(s, 32);
        if (quad == 0) hgs[nt * 16 + m16] = s;
    }
    __syncthreads();
    // ---- graph decoder + reaction aggregation ----
    float acc = gb1[lane];
#pragma unroll
    for (int k = 0; k < H; ++k)
        acc += hgs[k] * gW1[k * H + lane];
    float part = silu_f(acc) * gW2[lane];
#pragma unroll
    for (int off = 32; off > 0; off >>= 1)
        part += __shfl_down(part, off);
    if (lane == 0)
        atomAddF(&pred[rid[blockIdx.x]], (part + gb2[0]) * rsign[blockIdx.x]);
}

extern "C" void kernel_launch(void* const* d_in, const int* in_sizes, int n_in,
                              void* d_out, int out_size, void* d_ws, size_t ws_size,
                              hipStream_t stream) {
    const float* h0      = (const float*)d_in[0];
    const float* pos     = (const float*)d_in[1];
    const int*   edges   = (const int*)d_in[2];
    const float* nmask   = (const float*)d_in[3];
    const float* emask   = (const float*)d_in[4];
    const int*   rid     = (const int*)d_in[5];
    const float* rsign   = (const float*)d_in[6];
    const float* emb_w   = (const float*)d_in[7];
    const float* emb_b   = (const float*)d_in[8];
    const float* edge_w1 = (const float*)d_in[9];
    const float* edge_b1 = (const float*)d_in[10];
    const float* edge_w2 = (const float*)d_in[11];
    const float* edge_b2 = (const float*)d_in[12];
    const float* node_w1 = (const float*)d_in[13];
    const float* node_b1 = (const float*)d_in[14];
    const float* node_w2 = (const float*)d_in[15];
    const float* node_b2 = (const float*)d_in[16];
    const float* dec_w1  = (const float*)d_in[17];
    const float* dec_b1  = (const float*)d_in[18];
    const float* dec_w2  = (const float*)d_in[19];
    const float* dec_b2  = (const float*)d_in[20];
    const float* g_w1    = (const float*)d_in[21];
    const float* g_b1    = (const float*)d_in[22];
    const float* g_w2    = (const float*)d_in[23];
    const float* g_b2    = (const float*)d_in[24];

    float* h      = (float*)d_ws;            // N*H
    float* agg    = h + N_NODES * H;         // N*H
    float* PA     = agg + N_NODES * H;       // N*H
    float* PB     = PA + N_NODES * H;        // N*H
    float4* csrQ  = (float4*)(PB + N_NODES * H);   // E float4 (16B aligned)
    int*   deg    = (int*)(csrQ + N_EDGES);  // N
    int*   off    = deg + N_NODES;           // N
    int*   bsum   = off + N_NODES;           // 256
    int*   bbase  = bsum + 256;              // 256
    int*   nstart = bbase + 256;             // N+1
    int*   cursor = nstart + N_NODES + 1;    // N
    short* wsW    = (short*)((((uintptr_t)(cursor + N_NODES)) + 255) & ~(uintptr_t)255);
    float* pred   = (float*)d_out;

    hipMemsetAsync(d_out, 0, R_REACT * sizeof(float), stream);
    hipMemsetAsync(deg, 0, N_NODES * sizeof(int), stream);

    k_prepw<<<228, 64, 0, stream>>>(edge_w1, edge_w2, node_w1, node_w2,
                                    dec_w1, dec_w2, emb_w, wsW);
    k_hist<<<N_EDGES / 256, 256, 0, stream>>>(edges, deg);
    k_scan_blk<<<256, 128, 0, stream>>>(deg, off, bsum);
    k_scan_top<<<1, 256, 0, stream>>>(bsum, bbase);
    k_cursor<<<N_NODES / 256, 256, 0, stream>>>(off, bbase, nstart, cursor);
    k_fill<<<N_EDGES / 256, 256, 0, stream>>>(edges, pos, emask, cursor, csrQ);
    k_embed_proj<<<N_NODES / 16, 64, 0, stream>>>(
        h0, wsW + WEMB, emb_b, wsW + WPROJ, edge_b1, h, PA, PB);

    for (int i = 0; i < L_LAYERS; ++i) {
        k_edge6<<<N_NODES / NPBLK, 256, 0, stream>>>(
            PA, PB, nstart, csrQ,
            edge_w1 + i * EIN * H,
            wsW + WE2 + i * 8192, edge_b2 + i * H, agg);
        if (i < L_LAYERS - 1) {
            k_node_proj<<<N_NODES / 16, 64, 0, stream>>>(
                h, agg, h0,
                wsW + WN1 + i * 20480, node_b1 + i * H,
                wsW + WN2 + i * 8192,  node_b2 + i * H,
                wsW + WPROJ + (i + 1) * 16384, edge_b1 + (i + 1) * H,
                PA, PB);
        } else {
            k_node_dec_graph<<<N_NODES / 16, 64, 0, stream>>>(
                h, agg, h0,
                wsW + WN1 + i * 20480, node_b1 + i * H,
                wsW + WN2 + i * 8192,  node_b2 + i * H,
                wsW + WD1, dec_b1, wsW + WD2, dec_b2,
                nmask, g_w1, g_b1, g_w2, g_b2, rid, rsign, pred);
        }
    }
}

// Round 12
// 482.730 us; speedup vs baseline: 1.0606x; 1.0606x over previous
//
#include <hip/hip_runtime.h>
#include <math.h>
#include <stdint.h>

#define N_NODES 32768
#define N_EDGES 491520
#define F_IN    11
#define H       64
#define G_GRAPHS 2048
#define NN_PER_G 16
#define R_REACT 1024
#define L_LAYERS 4
#define EIN     129   // 2H+1
#define NIN     139   // 2H+F
#define NPBLK   32    // nodes per k_edge6 block

// preconverted-weight workspace layout (in shorts)
#define WPROJ 0                 // 4 layers x 16384 (16 frags hi @0, lo @8192)
#define WE2   65536             // 4 layers x 8192  (8 frags hi @0, lo @4096)
#define WN1   98304             // 4 layers x 20480 (20 frags hi @0, lo @10240)
#define WN2   180224            // 4 layers x 8192
#define WD1   212992            // 8192
#define WD2   221184            // 8192
#define WEMB  229376            // 4096 (4 frags hi @0, lo @2048)
#define WTOT  233472

typedef __attribute__((ext_vector_type(8))) short short8;
typedef __attribute__((ext_vector_type(4))) float f32x4;

__device__ __forceinline__ float silu_f(float x) {
    return x * __builtin_amdgcn_rcpf(1.0f + __expf(-x));
}
__device__ __forceinline__ void atomAddF(float* p, float v) {
    unsafeAtomicAdd(p, v);
}
__device__ __forceinline__ float bf2f(unsigned short b) {
    union { float f; unsigned u; } v; v.u = ((unsigned)b) << 16;
    return v.f;
}
__device__ __forceinline__ unsigned short f2bf(float x) {   // RNE
    union { float f; unsigned u; } v; v.f = x;
    unsigned r = v.u + 0x7FFFu + ((v.u >> 16) & 1u);
    return (unsigned short)(r >> 16);
}
// RNE split (weights, cold path)
__device__ __forceinline__ void splitbf(float x, unsigned short& hi, unsigned short& lo) {
    hi = f2bf(x);
    lo = f2bf(x - bf2f(hi));
}
// truncation split (hot path; validated absmax 3e-5)
__device__ __forceinline__ void splitbf_t(float x, unsigned short& hi, unsigned short& lo) {
    union { float f; unsigned u; } v; v.f = x;
    hi = (unsigned short)(v.u >> 16);
    union { float f; unsigned u; } w; w.f = x - bf2f(hi);
    lo = (unsigned short)(w.u >> 16);
}

// ---------------- weight fragment pre-conversion (runs once/call) --------
__global__ __launch_bounds__(64) void k_prepw(
        const float* __restrict__ ew1, const float* __restrict__ ew2,
        const float* __restrict__ nw1, const float* __restrict__ nw2,
        const float* __restrict__ dw1, const float* __restrict__ dw2,
        const float* __restrict__ embw,
        short* __restrict__ wsW) {
    const int b = blockIdx.x;
    const int lane = threadIdx.x;
    const int quad = lane >> 4, m16 = lane & 15;
    short8 h8, l8;
    short* base; int fidx, half;

    if (b < 64) {                       // edge_w1 rows 0..127 (proj)
        int l = b >> 4, f = b & 15;
        int nt = f >> 1, kf = f & 1;
#pragma unroll
        for (int j = 0; j < 8; ++j) {
            int row = (nt >= 4 ? 64 : 0) + kf * 32 + quad * 8 + j;
            unsigned short hi, lo;
            splitbf(ew1[l * EIN * H + row * H + (nt & 3) * 16 + m16], hi, lo);
            h8[j] = (short)hi; l8[j] = (short)lo;
        }
        base = wsW + WPROJ + l * 16384; fidx = f; half = 8192;
    } else if (b < 96) {                // edge_w2
        int bb = b - 64; int l = bb >> 3, f = bb & 7;
        int nt = f >> 1, kf = f & 1;
#pragma unroll
        for (int j = 0; j < 8; ++j) {
            int row = kf * 32 + quad * 8 + j;
            unsigned short hi, lo;
            splitbf(ew2[l * H * H + row * H + nt * 16 + m16], hi, lo);
            h8[j] = (short)hi; l8[j] = (short)lo;
        }
        base = wsW + WE2 + l * 8192; fidx = f; half = 4096;
    } else if (b < 176) {               // node_w1 (rows padded to 160)
        int bb = b - 96; int l = bb / 20, f = bb % 20;
        int nt = f / 5, kf = f % 5;
#pragma unroll
        for (int j = 0; j < 8; ++j) {
            int row = kf * 32 + quad * 8 + j;
            float w = (row < NIN) ? nw1[l * NIN * H + row * H + nt * 16 + m16] : 0.0f;
            unsigned short hi, lo; splitbf(w, hi, lo);
            h8[j] = (short)hi; l8[j] = (short)lo;
        }
        base = wsW + WN1 + l * 20480; fidx = f; half = 10240;
    } else if (b < 208) {               // node_w2
        int bb = b - 176; int l = bb >> 3, f = bb & 7;
        int nt = f >> 1, kf = f & 1;
#pragma unroll
        for (int j = 0; j < 8; ++j) {
            int row = kf * 32 + quad * 8 + j;
            unsigned short hi, lo;
            splitbf(nw2[l * H * H + row * H + nt * 16 + m16], hi, lo);
            h8[j] = (short)hi; l8[j] = (short)lo;
        }
        base = wsW + WN2 + l * 8192; fidx = f; half = 4096;
    } else if (b < 216) {               // dec_w1
        int f = b - 208;
        int nt = f >> 1, kf = f & 1;
#pragma unroll
        for (int j = 0; j < 8; ++j) {
            int row = kf * 32 + quad * 8 + j;
            unsigned short hi, lo;
            splitbf(dw1[row * H + nt * 16 + m16], hi, lo);
            h8[j] = (short)hi; l8[j] = (short)lo;
        }
        base = wsW + WD1; fidx = f; half = 4096;
    } else if (b < 224) {               // dec_w2
        int f = b - 216;
        int nt = f >> 1, kf = f & 1;
#pragma unroll
        for (int j = 0; j < 8; ++j) {
            int row = kf * 32 + quad * 8 + j;
            unsigned short hi, lo;
            splitbf(dw2[row * H + nt * 16 + m16], hi, lo);
            h8[j] = (short)hi; l8[j] = (short)lo;
        }
        base = wsW + WD2; fidx = f; half = 4096;
    } else {                            // emb_w (K=32 frag, rows >= F_IN zero)
        int f = b - 224;                // = nt
#pragma unroll
        for (int j = 0; j < 8; ++j) {
            int row = quad * 8 + j;
            float w = (row < F_IN) ? embw[row * H + f * 16 + m16] : 0.0f;
            unsigned short hi, lo; splitbf(w, hi, lo);
            h8[j] = (short)hi; l8[j] = (short)lo;
        }
        base = wsW + WEMB; fidx = f; half = 2048;
    }
    *(short8*)(base + (fidx * 64 + lane) * 8) = h8;
    *(short8*)(base + half + (fidx * 64 + lane) * 8) = l8;
}

// ---------------- CSR build ----------------
__global__ __launch_bounds__(256) void k_hist(
        const int* __restrict__ edges, int* __restrict__ deg) {
    int e = blockIdx.x * 256 + threadIdx.x;
    atomicAdd(&deg[edges[e]], 1);
}

__global__ __launch_bounds__(128) void k_scan_blk(
        const int* __restrict__ deg, int* __restrict__ off,
        int* __restrict__ bsum) {
    __shared__ int sd[128];
    int b = blockIdx.x;
    sd[threadIdx.x] = deg[b * 128 + threadIdx.x];
    __syncthreads();
    if (threadIdx.x == 0) {
        int s = 0;
        for (int i = 0; i < 128; ++i) { int d = sd[i]; sd[i] = s; s += d; }
        bsum[b] = s;
    }
    __syncthreads();
    off[b * 128 + threadIdx.x] = sd[threadIdx.x];
}

__global__ __launch_bounds__(256) void k_scan_top(
        const int* __restrict__ bsum, int* __restrict__ bbase) {
    __shared__ int sb[256];
    sb[threadIdx.x] = bsum[threadIdx.x];
    __syncthreads();
    if (threadIdx.x == 0) {
        int s = 0;
        for (int i = 0; i < 256; ++i) { int d = sb[i]; sb[i] = s; s += d; }
    }
    __syncthreads();
    bbase[threadIdx.x] = sb[threadIdx.x];
}

__global__ __launch_bounds__(256) void k_cursor(
        const int* __restrict__ off, const int* __restrict__ bbase,
        int* __restrict__ nstart, int* __restrict__ cursor) {
    int n = blockIdx.x * 256 + threadIdx.x;
    int ns = off[n] + bbase[n >> 7];
    nstart[n] = ns;
    cursor[n] = ns;
    if (n == 0) nstart[N_NODES] = N_EDGES;
}

// fill: radial fused + PACKED meta (one float4/edge: {pk, rad, mask, 0})
__global__ __launch_bounds__(256) void k_fill(
        const int* __restrict__ edges, const float* __restrict__ posi,
        const float* __restrict__ emask, int* __restrict__ cursor,
        float4* __restrict__ csrQ) {
    int e = blockIdx.x * 256 + threadIdx.x;
    int r = edges[e], c = edges[N_EDGES + e];
    float dx = posi[r * 3 + 0] - posi[c * 3 + 0];
    float dy = posi[r * 3 + 1] - posi[c * 3 + 1];
    float dz = posi[r * 3 + 2] - posi[c * 3 + 2];
    float rad = dx * dx + dy * dy + dz * dz;
    int p = atomicAdd(&cursor[r], 1);
    int pk = c | ((r & (NPBLK - 1)) << 16);  // col | row_local
    csrQ[p] = make_float4(__int_as_float(pk), rad, emask[e], 0.0f);
}

// ---------------- embed + layer-0 projection (fused) ---------------------
__global__ __launch_bounds__(64, 2) void k_embed_proj(
        const float* __restrict__ h0, const short* __restrict__ wEmb,
        const float* __restrict__ emb_b,
        const short* __restrict__ wP, const float* __restrict__ eb1,
        float* __restrict__ h, float* __restrict__ PA, float* __restrict__ PB) {
    const int lane = threadIdx.x;
    const int quad = lane >> 4, m16 = lane & 15;
    const int nb = blockIdx.x * 16;
    __shared__ float tld[16 * 68];

    float a0[8];
    const float* h0p = h0 + (nb + m16) * F_IN;
#pragma unroll
    for (int j = 0; j < 8; ++j) {
        int kk = quad * 8 + j;
        a0[j] = (kk < F_IN) ? h0p[kk] : 0.0f;
    }
    short8 A0h, A0l;
#pragma unroll
    for (int j = 0; j < 8; ++j) {
        unsigned short hi, lo; splitbf_t(a0[j], hi, lo);
        A0h[j] = (short)hi; A0l[j] = (short)lo;
    }
    float ebv[4];
#pragma unroll
    for (int nt = 0; nt < 4; ++nt) ebv[nt] = emb_b[nt * 16 + m16];

#pragma unroll
    for (int nt = 0; nt < 4; ++nt) {
        short8 bh = *(const short8*)(wEmb + (nt * 64 + lane) * 8);
        short8 bl = *(const short8*)(wEmb + 2048 + (nt * 64 + lane) * 8);
        f32x4 a = {0.0f, 0.0f, 0.0f, 0.0f};
        a = __builtin_amdgcn_mfma_f32_16x16x32_bf16(A0h, bh, a, 0, 0, 0);
        a = __builtin_amdgcn_mfma_f32_16x16x32_bf16(A0h, bl, a, 0, 0, 0);
        a = __builtin_amdgcn_mfma_f32_16x16x32_bf16(A0l, bh, a, 0, 0, 0);
#pragma unroll
        for (int r4 = 0; r4 < 4; ++r4) {
            const int node = nb + quad * 4 + r4;
            float hv = a[r4] + ebv[nt];
            h[node * H + nt * 16 + m16] = hv;
            tld[(quad * 4 + r4) * 68 + nt * 16 + m16] = hv;
        }
    }
    __syncthreads();
    float av[16];
    *(float4*)&av[0]  = *(const float4*)&tld[m16 * 68 + quad * 8 + 0];
    *(float4*)&av[4]  = *(const float4*)&tld[m16 * 68 + quad * 8 + 4];
    *(float4*)&av[8]  = *(const float4*)&tld[m16 * 68 + quad * 8 + 32];
    *(float4*)&av[12] = *(const float4*)&tld[m16 * 68 + quad * 8 + 36];
    short8 Ah0, Ah1, Al0, Al1;
#pragma unroll
    for (int j = 0; j < 8; ++j) {
        unsigned short hi, lo;
        splitbf_t(av[j], hi, lo);     Ah0[j] = (short)hi; Al0[j] = (short)lo;
        splitbf_t(av[8 + j], hi, lo); Ah1[j] = (short)hi; Al1[j] = (short)lo;
    }
    float b1v[4];
#pragma unroll
    for (int nt = 0; nt < 4; ++nt) b1v[nt] = eb1[nt * 16 + m16];
#pragma unroll
    for (int nt = 0; nt < 8; ++nt) {
        short8 bh0 = *(const short8*)(wP + ((nt*2+0) * 64 + lane) * 8);
        short8 bh1 = *(const short8*)(wP + ((nt*2+1) * 64 + lane) * 8);
        short8 bl0 = *(const short8*)(wP + 8192 + ((nt*2+0) * 64 + lane) * 8);
        short8 bl1 = *(const short8*)(wP + 8192 + ((nt*2+1) * 64 + lane) * 8);
        f32x4 a = {0.0f, 0.0f, 0.0f, 0.0f};
        a = __builtin_amdgcn_mfma_f32_16x16x32_bf16(Ah0, bh0, a, 0, 0, 0);
        a = __builtin_amdgcn_mfma_f32_16x16x32_bf16(Ah1, bh1, a, 0, 0, 0);
        a = __builtin_amdgcn_mfma_f32_16x16x32_bf16(Ah0, bl0, a, 0, 0, 0);
        a = __builtin_amdgcn_mfma_f32_16x16x32_bf16(Ah1, bl1, a, 0, 0, 0);
        a = __builtin_amdgcn_mfma_f32_16x16x32_bf16(Al0, bh0, a, 0, 0, 0);
        a = __builtin_amdgcn_mfma_f32_16x16x32_bf16(Al1, bh1, a, 0, 0, 0);
#pragma unroll
        for (int r4 = 0; r4 < 4; ++r4) {
            const int node = nb + quad * 4 + r4;
            if (nt < 4)
                PA[node * H + nt * 16 + m16] = a[r4] + b1v[nt];
            else
                PB[node * H + (nt - 4) * 16 + m16] = a[r4];
        }
    }
}

// ------ edge MLP: R2 structure (3-stage meta pipeline) + packed meta -----
__global__ __launch_bounds__(256, 2) void k_edge6(
        const float* __restrict__ PA, const float* __restrict__ PB,
        const int* __restrict__ nstart, const float4* __restrict__ csrQ,
        const float* __restrict__ W1,   // only row 128 (w1c) used
        const short* __restrict__ wE2, const float* __restrict__ b2,
        float* __restrict__ agg) {
    const int tid = threadIdx.x;
    const int lane = tid & 63, wave = tid >> 6;
    const int quad = lane >> 4, m16 = lane & 15;
    const int n0 = blockIdx.x * NPBLK;

    __shared__ float aggld[NPBLK * 68];
    for (int i = tid; i < NPBLK * 68; i += 256) aggld[i] = 0.0f;

    short8 Bh[8], Bl[8];
#pragma unroll
    for (int f = 0; f < 8; ++f) {
        Bh[f] = *(const short8*)(wE2 + (f * 64 + lane) * 8);
        Bl[f] = *(const short8*)(wE2 + 4096 + (f * 64 + lane) * 8);
    }
    float w1cr[16];
#pragma unroll
    for (int i = 0; i < 16; ++i) {
        int k = (i < 8) ? (quad * 8 + i) : (32 + quad * 8 + (i - 8));
        w1cr[i] = W1[128 * H + k];
    }
    float b2v[4];
#pragma unroll
    for (int nt = 0; nt < 4; ++nt) b2v[nt] = b2[nt * 16 + m16];

    const int start = nstart[n0];
    const int end   = nstart[n0 + NPBLK];
    __syncthreads();

    const int ntiles = (end - start + 15) >> 4;

    // A: data fully resident; B: meta resident, bv gather at loop top;
    // C: meta loads in flight during compute.
    int   pkA = 0, pkB = 0;
    float radA = 0.0f, radB = 0.0f;
    float avA[16], bvA[16];

    int tA = wave;
    bool haveA = tA < ntiles;
    if (haveA) {
        const int idx = start + tA * 16 + m16;
        const int ss  = min(idx, N_EDGES - 1);
        float4 q = csrQ[ss];
        pkA  = __float_as_int(q.x);
        radA = q.y;
        const int c  = pkA & 0xFFFF;
        const int rl = pkA >> 16;
        const float* par = PA + (n0 + rl) * H + quad * 8;
        const float* pbr = PB + c * H + quad * 8;
        *(float4*)&avA[0]  = *(const float4*)(par + 0);
        *(float4*)&avA[4]  = *(const float4*)(par + 4);
        *(float4*)&avA[8]  = *(const float4*)(par + 32);
        *(float4*)&avA[12] = *(const float4*)(par + 36);
        *(float4*)&bvA[0]  = *(const float4*)(pbr + 0);
        *(float4*)&bvA[4]  = *(const float4*)(pbr + 4);
        *(float4*)&bvA[8]  = *(const float4*)(pbr + 32);
        *(float4*)&bvA[12] = *(const float4*)(pbr + 36);
    }
    int tB = tA + 4;
    bool haveB = tB < ntiles;
    if (haveB) {
        const int idx = start + tB * 16 + m16;
        const int ss  = min(idx, N_EDGES - 1);
        float4 q = csrQ[ss];
        pkB  = __float_as_int(q.x);
        radB = q.y;
    }

    while (haveA) {
        // 1. gather B data (meta already resident)
        float bvB[16];
        if (haveB) {
            const int c = pkB & 0xFFFF;
            const float* pbr = PB + c * H + quad * 8;
            *(float4*)&bvB[0]  = *(const float4*)(pbr + 0);
            *(float4*)&bvB[4]  = *(const float4*)(pbr + 4);
            *(float4*)&bvB[8]  = *(const float4*)(pbr + 32);
            *(float4*)&bvB[12] = *(const float4*)(pbr + 36);
        }
        // 2. issue meta load for C (packed: one float4)
        const int tC = tB + 4;
        const bool haveC = tC < ntiles;
        int pkC = 0; float radC = 0.0f;
        if (haveC) {
            const int idx = start + tC * 16 + m16;
            const int ss  = min(idx, N_EDGES - 1);
            float4 q = csrQ[ss];
            pkC  = __float_as_int(q.x);
            radC = q.y;
        }
        // 3. per-quad meta for tile A (packed: 4 float4 loads, L1-warm)
        int rlq[4]; float mkq[4];
        const int sb = start + tA * 16 + quad * 4;
#pragma unroll
        for (int r4 = 0; r4 < 4; ++r4) {
            int s = sb + r4, s2 = min(s, N_EDGES - 1);
            float4 q = csrQ[s2];
            rlq[r4] = __float_as_int(q.x) >> 16;
            mkq[r4] = (s < end) ? q.z : 0.0f;
        }

        // 4. compute tile A
        short8 Ah0, Ah1, Al0, Al1;
#pragma unroll
        for (int i = 0; i < 8; ++i) {
            unsigned short hi, lo;
            splitbf_t(silu_f(avA[i] + bvA[i] + radA * w1cr[i]), hi, lo);
            Ah0[i] = (short)hi; Al0[i] = (short)lo;
            splitbf_t(silu_f(avA[8+i] + bvA[8+i] + radA * w1cr[8+i]), hi, lo);
            Ah1[i] = (short)hi; Al1[i] = (short)lo;
        }
        f32x4 acc[4];
#pragma unroll
        for (int nt = 0; nt < 4; ++nt) {
            f32x4 a = {0.0f, 0.0f, 0.0f, 0.0f};
            a = __builtin_amdgcn_mfma_f32_16x16x32_bf16(Ah0, Bh[nt*2+0], a, 0, 0, 0);
            a = __builtin_amdgcn_mfma_f32_16x16x32_bf16(Ah1, Bh[nt*2+1], a, 0, 0, 0);
            a = __builtin_amdgcn_mfma_f32_16x16x32_bf16(Ah0, Bl[nt*2+0], a, 0, 0, 0);
            a = __builtin_amdgcn_mfma_f32_16x16x32_bf16(Ah1, Bl[nt*2+1], a, 0, 0, 0);
            a = __builtin_amdgcn_mfma_f32_16x16x32_bf16(Al0, Bh[nt*2+0], a, 0, 0, 0);
            a = __builtin_amdgcn_mfma_f32_16x16x32_bf16(Al1, Bh[nt*2+1], a, 0, 0, 0);
            acc[nt] = a;
        }

        // 5. epilogue: run-reduced LDS atomics
#pragma unroll
        for (int nt = 0; nt < 4; ++nt) {
            float oo[4];
#pragma unroll
            for (int r4 = 0; r4 < 4; ++r4)
                oo[r4] = silu_f(acc[nt][r4] + b2v[nt]) * mkq[r4];
            int cur = rlq[0]; float s = oo[0];
#pragma unroll
            for (int r4 = 1; r4 < 4; ++r4) {
                if (rlq[r4] == cur) { s += oo[r4]; }
                else {
                    atomicAdd(&aggld[cur * 68 + nt * 16 + m16], s);
                    cur = rlq[r4]; s = oo[r4];
                }
            }
            atomicAdd(&aggld[cur * 68 + nt * 16 + m16], s);
        }

        // 6. shift pipeline (avA reload is L1-hot; late is fine — R2/R6 A/B)
        if (haveB) {
            const int rl = pkB >> 16;
            const float* par = PA + (n0 + rl) * H + quad * 8;
            *(float4*)&avA[0]  = *(const float4*)(par + 0);
            *(float4*)&avA[4]  = *(const float4*)(par + 4);
            *(float4*)&avA[8]  = *(const float4*)(par + 32);
            *(float4*)&avA[12] = *(const float4*)(par + 36);
#pragma unroll
            for (int i = 0; i < 16; ++i) bvA[i] = bvB[i];
            pkA = pkB; radA = radB;
        }
        pkB = pkC; radB = radC;
        tA = tB; tB = tC; haveA = haveB; haveB = haveC;
    }

    __syncthreads();
#pragma unroll
    for (int i = tid; i < NPBLK * 16; i += 256) {
        int n = i >> 4, cb = (i & 15) << 2;
        *(float4*)&agg[(n0 + n) * H + cb] = *(const float4*)&aggld[n * 68 + cb];
    }
}

// ---------------- node MLP + next-layer projection (fused) ---------------
__global__ __launch_bounds__(64, 2) void k_node_proj(
        float* __restrict__ h, const float* __restrict__ agg,
        const float* __restrict__ h0,
        const short* __restrict__ wN1, const float* __restrict__ b1,
        const short* __restrict__ wN2, const float* __restrict__ b2,
        const short* __restrict__ wPn, const float* __restrict__ eb1n,
        float* __restrict__ PA, float* __restrict__ PB) {
    const int lane = threadIdx.x;
    const int quad = lane >> 4, m16 = lane & 15;
    const int nb = blockIdx.x * 16;

    float b1v[4], b2v[4];
#pragma unroll
    for (int nt = 0; nt < 4; ++nt) {
        b1v[nt] = b1[nt * 16 + m16];
        b2v[nt] = b2[nt * 16 + m16];
    }
    __shared__ float tld[16 * 68];

    // ---- node MLP layer 1 ----
    float a1[5][8];
    const float* hp = h + (nb + m16) * H + quad * 8;
    const float* ap = agg + (nb + m16) * H + quad * 8;
    *(float4*)&a1[0][0] = *(const float4*)(hp + 0);
    *(float4*)&a1[0][4] = *(const float4*)(hp + 4);
    *(float4*)&a1[1][0] = *(const float4*)(hp + 32);
    *(float4*)&a1[1][4] = *(const float4*)(hp + 36);
    *(float4*)&a1[2][0] = *(const float4*)(ap + 0);
    *(float4*)&a1[2][4] = *(const float4*)(ap + 4);
    *(float4*)&a1[3][0] = *(const float4*)(ap + 32);
    *(float4*)&a1[3][4] = *(const float4*)(ap + 36);
    const float* h0p = h0 + (nb + m16) * F_IN;
#pragma unroll
    for (int j = 0; j < 8; ++j) {
        int kk = quad * 8 + j;
        a1[4][j] = (kk < F_IN) ? h0p[kk] : 0.0f;
    }
    short8 A1h[5], A1l[5];
#pragma unroll
    for (int kf = 0; kf < 5; ++kf) {
        short8 ah, al;
#pragma unroll
        for (int j = 0; j < 8; ++j) {
            unsigned short hi, lo; splitbf_t(a1[kf][j], hi, lo);
            ah[j] = (short)hi; al[j] = (short)lo;
        }
        A1h[kf] = ah; A1l[kf] = al;
    }
#pragma unroll
    for (int nt = 0; nt < 4; ++nt) {
        short8 bh[5], bl[5];
#pragma unroll
        for (int kf = 0; kf < 5; ++kf) {
            bh[kf] = *(const short8*)(wN1 + ((nt*5+kf) * 64 + lane) * 8);
            bl[kf] = *(const short8*)(wN1 + 10240 + ((nt*5+kf) * 64 + lane) * 8);
        }
        f32x4 a = {0.0f, 0.0f, 0.0f, 0.0f};
#pragma unroll
        for (int kf = 0; kf < 5; ++kf)
            a = __builtin_amdgcn_mfma_f32_16x16x32_bf16(A1h[kf], bh[kf], a, 0, 0, 0);
#pragma unroll
        for (int kf = 0; kf < 5; ++kf)
            a = __builtin_amdgcn_mfma_f32_16x16x32_bf16(A1h[kf], bl[kf], a, 0, 0, 0);
#pragma unroll
        for (int kf = 0; kf < 5; ++kf)
            a = __builtin_amdgcn_mfma_f32_16x16x32_bf16(A1l[kf], bh[kf], a, 0, 0, 0);
#pragma unroll
        for (int r4 = 0; r4 < 4; ++r4)
            tld[(quad * 4 + r4) * 68 + nt * 16 + m16] = silu_f(a[r4] + b1v[nt]);
    }
    __syncthreads();
    // ---- node MLP layer 2 ----
    float a2[16];
    *(float4*)&a2[0]  = *(const float4*)&tld[m16 * 68 + quad * 8 + 0];
    *(float4*)&a2[4]  = *(const float4*)&tld[m16 * 68 + quad * 8 + 4];
    *(float4*)&a2[8]  = *(const float4*)&tld[m16 * 68 + quad * 8 + 32];
    *(float4*)&a2[12] = *(const float4*)&tld[m16 * 68 + quad * 8 + 36];
    short8 A2h0, A2h1, A2l0, A2l1;
#pragma unroll
    for (int j = 0; j < 8; ++j) {
        unsigned short hi, lo;
        splitbf_t(a2[j], hi, lo);     A2h0[j] = (short)hi; A2l0[j] = (short)lo;
        splitbf_t(a2[8+j], hi, lo);   A2h1[j] = (short)hi; A2l1[j] = (short)lo;
    }
    __syncthreads();   // a2 reads complete before tld overwritten
#pragma unroll
    for (int nt = 0; nt < 4; ++nt) {
        short8 bh0 = *(const short8*)(wN2 + ((nt*2+0) * 64 + lane) * 8);
        short8 bh1 = *(const short8*)(wN2 + ((nt*2+1) * 64 + lane) * 8);
        short8 bl0 = *(const short8*)(wN2 + 4096 + ((nt*2+0) * 64 + lane) * 8);
        short8 bl1 = *(const short8*)(wN2 + 4096 + ((nt*2+1) * 64 + lane) * 8);
        f32x4 a = {0.0f, 0.0f, 0.0f, 0.0f};
        a = __builtin_amdgcn_mfma_f32_16x16x32_bf16(A2h0, bh0, a, 0, 0, 0);
        a = __builtin_amdgcn_mfma_f32_16x16x32_bf16(A2h1, bh1, a, 0, 0, 0);
        a = __builtin_amdgcn_mfma_f32_16x16x32_bf16(A2h0, bl0, a, 0, 0, 0);
        a = __builtin_amdgcn_mfma_f32_16x16x32_bf16(A2h1, bl1, a, 0, 0, 0);
        a = __builtin_amdgcn_mfma_f32_16x16x32_bf16(A2l0, bh0, a, 0, 0, 0);
        a = __builtin_amdgcn_mfma_f32_16x16x32_bf16(A2l1, bh1, a, 0, 0, 0);
#pragma unroll
        for (int r4 = 0; r4 < 4; ++r4) {
            const int node = nb + quad * 4 + r4;
            float hv = a[r4] + b2v[nt];
            h[node * H + nt * 16 + m16] = hv;
            tld[(quad * 4 + r4) * 68 + nt * 16 + m16] = hv;
        }
    }
    __syncthreads();
    // ---- projection for next layer ----
    float av[16];
    *(float4*)&av[0]  = *(const float4*)&tld[m16 * 68 + quad * 8 + 0];
    *(float4*)&av[4]  = *(const float4*)&tld[m16 * 68 + quad * 8 + 4];
    *(float4*)&av[8]  = *(const float4*)&tld[m16 * 68 + quad * 8 + 32];
    *(float4*)&av[12] = *(const float4*)&tld[m16 * 68 + quad * 8 + 36];
    short8 Ph0, Ph1, Pl0, Pl1;
#pragma unroll
    for (int j = 0; j < 8; ++j) {
        unsigned short hi, lo;
        splitbf_t(av[j], hi, lo);     Ph0[j] = (short)hi; Pl0[j] = (short)lo;
        splitbf_t(av[8+j], hi, lo);   Ph1[j] = (short)hi; Pl1[j] = (short)lo;
    }
    float b1ev[4];
#pragma unroll
    for (int nt = 0; nt < 4; ++nt) b1ev[nt] = eb1n[nt * 16 + m16];
#pragma unroll
    for (int nt = 0; nt < 8; ++nt) {
        short8 bh0 = *(const short8*)(wPn + ((nt*2+0) * 64 + lane) * 8);
        short8 bh1 = *(const short8*)(wPn + ((nt*2+1) * 64 + lane) * 8);
        short8 bl0 = *(const short8*)(wPn + 8192 + ((nt*2+0) * 64 + lane) * 8);
        short8 bl1 = *(const short8*)(wPn + 8192 + ((nt*2+1) * 64 + lane) * 8);
        f32x4 a = {0.0f, 0.0f, 0.0f, 0.0f};
        a = __builtin_amdgcn_mfma_f32_16x16x32_bf16(Ph0, bh0, a, 0, 0, 0);
        a = __builtin_amdgcn_mfma_f32_16x16x32_bf16(Ph1, bh1, a, 0, 0, 0);
        a = __builtin_amdgcn_mfma_f32_16x16x32_bf16(Ph0, bl0, a, 0, 0, 0);
        a = __builtin_amdgcn_mfma_f32_16x16x32_bf16(Ph1, bl1, a, 0, 0, 0);
        a = __builtin_amdgcn_mfma_f32_16x16x32_bf16(Pl0, bh0, a, 0, 0, 0);
        a = __builtin_amdgcn_mfma_f32_16x16x32_bf16(Pl1, bh1, a, 0, 0, 0);
#pragma unroll
        for (int r4 = 0; r4 < 4; ++r4) {
            const int node = nb + quad * 4 + r4;
            if (nt < 4)
                PA[node * H + nt * 16 + m16] = a[r4] + b1ev[nt];
            else
                PB[node * H + (nt - 4) * 16 + m16] = a[r4];
        }
    }
}

// ------- layer-3 node MLP + node decoder + pool + graph dec + reaction ---
__global__ __launch_bounds__(64, 2) void k_node_dec_graph(
        const float* __restrict__ h, const float* __restrict__ agg,
        const float* __restrict__ h0,
        const short* __restrict__ wN1, const float* __restrict__ b1,
        const short* __restrict__ wN2, const float* __restrict__ b2,
        const short* __restrict__ wD1, const float* __restrict__ db1,
        const short* __restrict__ wD2, const float* __restrict__ db2,
        const float* __restrict__ nmask,
        const float* __restrict__ gW1, const float* __restrict__ gb1,
        const float* __restrict__ gW2, const float* __restrict__ gb2,
        const int* __restrict__ rid, const float* __restrict__ rsign,
        float* __restrict__ pred) {
    const int lane = threadIdx.x;
    const int quad = lane >> 4, m16 = lane & 15;
    const int nb = blockIdx.x * 16;

    float b1v[4], b2v[4], db1v[4], db2v[4];
#pragma unroll
    for (int nt = 0; nt < 4; ++nt) {
        b1v[nt]  = b1[nt * 16 + m16];
        b2v[nt]  = b2[nt * 16 + m16];
        db1v[nt] = db1[nt * 16 + m16];
        db2v[nt] = db2[nt * 16 + m16];
    }
    float nm[4];
#pragma unroll
    for (int r4 = 0; r4 < 4; ++r4) nm[r4] = nmask[nb + quad * 4 + r4];

    __shared__ float tld[16 * 68];
    __shared__ __align__(16) float hgs[64];

    // ---- node MLP layer 1 ----
    float a1[5][8];
    const float* hp = h + (nb + m16) * H + quad * 8;
    const float* ap = agg + (nb + m16) * H + quad * 8;
    *(float4*)&a1[0][0] = *(const float4*)(hp + 0);
    *(float4*)&a1[0][4] = *(const float4*)(hp + 4);
    *(float4*)&a1[1][0] = *(const float4*)(hp + 32);
    *(float4*)&a1[1][4] = *(const float4*)(hp + 36);
    *(float4*)&a1[2][0] = *(const float4*)(ap + 0);
    *(float4*)&a1[2][4] = *(const float4*)(ap + 4);
    *(float4*)&a1[3][0] = *(const float4*)(ap + 32);
    *(float4*)&a1[3][4] = *(const float4*)(ap + 36);
    const float* h0p = h0 + (nb + m16) * F_IN;
#pragma unroll
    for (int j = 0; j < 8; ++j) {
        int kk = quad * 8 + j;
        a1[4][j] = (kk < F_IN) ? h0p[kk] : 0.0f;
    }
    short8 A1h[5], A1l[5];
#pragma unroll
    for (int kf = 0; kf < 5; ++kf) {
        short8 ah, al;
#pragma unroll
        for (int j = 0; j < 8; ++j) {
            unsigned short hi, lo; splitbf_t(a1[kf][j], hi, lo);
            ah[j] = (short)hi; al[j] = (short)lo;
        }
        A1h[kf] = ah; A1l[kf] = al;
    }
#pragma unroll
    for (int nt = 0; nt < 4; ++nt) {
        short8 bh[5], bl[5];
#pragma unroll
        for (int kf = 0; kf < 5; ++kf) {
            bh[kf] = *(const short8*)(wN1 + ((nt*5+kf) * 64 + lane) * 8);
            bl[kf] = *(const short8*)(wN1 + 10240 + ((nt*5+kf) * 64 + lane) * 8);
        }
        f32x4 a = {0.0f, 0.0f, 0.0f, 0.0f};
#pragma unroll
        for (int kf = 0; kf < 5; ++kf)
            a = __builtin_amdgcn_mfma_f32_16x16x32_bf16(A1h[kf], bh[kf], a, 0, 0, 0);
#pragma unroll
        for (int kf = 0; kf < 5; ++kf)
            a = __builtin_amdgcn_mfma_f32_16x16x32_bf16(A1h[kf], bl[kf], a, 0, 0, 0);
#pragma unroll
        for (int kf = 0; kf < 5; ++kf)
            a = __builtin_amdgcn_mfma_f32_16x16x32_bf16(A1l[kf], bh[kf], a, 0, 0, 0);
#pragma unroll
        for (int r4 = 0; r4 < 4; ++r4)
            tld[(quad * 4 + r4) * 68 + nt * 16 + m16] = silu_f(a[r4] + b1v[nt]);
    }
    __syncthreads();
    // ---- node MLP layer 2 (h_new stays in LDS) ----
    float a2[16];
    *(float4*)&a2[0]  = *(const float4*)&tld[m16 * 68 + quad * 8 + 0];
    *(float4*)&a2[4]  = *(const float4*)&tld[m16 * 68 + quad * 8 + 4];
    *(float4*)&a2[8]  = *(const float4*)&tld[m16 * 68 + quad * 8 + 32];
    *(float4*)&a2[12] = *(const float4*)&tld[m16 * 68 + quad * 8 + 36];
    short8 A2h0, A2h1, A2l0, A2l1;
#pragma unroll
    for (int j = 0; j < 8; ++j) {
        unsigned short hi, lo;
        splitbf_t(a2[j], hi, lo);     A2h0[j] = (short)hi; A2l0[j] = (short)lo;
        splitbf_t(a2[8+j], hi, lo);   A2h1[j] = (short)hi; A2l1[j] = (short)lo;
    }
    __syncthreads();
#pragma unroll
    for (int nt = 0; nt < 4; ++nt) {
        short8 bh0 = *(const short8*)(wN2 + ((nt*2+0) * 64 + lane) * 8);
        short8 bh1 = *(const short8*)(wN2 + ((nt*2+1) * 64 + lane) * 8);
        short8 bl0 = *(const short8*)(wN2 + 4096 + ((nt*2+0) * 64 + lane) * 8);
        short8 bl1 = *(const short8*)(wN2 + 4096 + ((nt*2+1) * 64 + lane) * 8);
        f32x4 a = {0.0f, 0.0f, 0.0f, 0.0f};
        a = __builtin_amdgcn_mfma_f32_16x16x32_bf16(A2h0, bh0, a, 0, 0, 0);
        a = __builtin_amdgcn_mfma_f32_16x16x32_bf16(A2h1, bh1, a, 0, 0, 0);
        a = __builtin_amdgcn_mfma_f32_16x16x32_bf16(A2h0, bl0, a, 0, 0, 0);
        a = __builtin_amdgcn_mfma_f32_16x16x32_bf16(A2h1, bl1, a, 0, 0, 0);
        a = __builtin_amdgcn_mfma_f32_16x16x32_bf16(A2l0, bh0, a, 0, 0, 0);
        a = __builtin_amdgcn_mfma_f32_16x16x32_bf16(A2l1, bh1, a, 0, 0, 0);
#pragma unroll
        for (int r4 = 0; r4 < 4; ++r4)
            tld[(quad * 4 + r4) * 68 + nt * 16 + m16] = a[r4] + b2v[nt];
    }
    __syncthreads();
    // ---- decoder layer 1 ----
    float av[16];
    *(float4*)&av[0]  = *(const float4*)&tld[m16 * 68 + quad * 8 + 0];
    *(float4*)&av[4]  = *(const float4*)&tld[m16 * 68 + quad * 8 + 4];
    *(float4*)&av[8]  = *(const float4*)&tld[m16 * 68 + quad * 8 + 32];
    *(float4*)&av[12] = *(const float4*)&tld[m16 * 68 + quad * 8 + 36];
    short8 Dh0, Dh1, Dl0, Dl1;
#pragma unroll
    for (int j = 0; j < 8; ++j) {
        unsigned short hi, lo;
        splitbf_t(av[j], hi, lo);     Dh0[j] = (short)hi; Dl0[j] = (short)lo;
        splitbf_t(av[8+j], hi, lo);   Dh1[j] = (short)hi; Dl1[j] = (short)lo;
    }
    __syncthreads();
#pragma unroll
    for (int nt = 0; nt < 4; ++nt) {
        short8 bh0 = *(const short8*)(wD1 + ((nt*2+0) * 64 + lane) * 8);
        short8 bh1 = *(const short8*)(wD1 + ((nt*2+1) * 64 + lane) * 8);
        short8 bl0 = *(const short8*)(wD1 + 4096 + ((nt*2+0) * 64 + lane) * 8);
        short8 bl1 = *(const short8*)(wD1 + 4096 + ((nt*2+1) * 64 + lane) * 8);
        f32x4 a = {0.0f, 0.0f, 0.0f, 0.0f};
        a = __builtin_amdgcn_mfma_f32_16x16x32_bf16(Dh0, bh0, a, 0, 0, 0);
        a = __builtin_amdgcn_mfma_f32_16x16x32_bf16(Dh1, bh1, a, 0, 0, 0);
        a = __builtin_amdgcn_mfma_f32_16x16x32_bf16(Dh0, bl0, a, 0, 0, 0);
        a = __builtin_amdgcn_mfma_f32_16x16x32_bf16(Dh1, bl1, a, 0, 0, 0);
        a = __builtin_amdgcn_mfma_f32_16x16x32_bf16(Dl0, bh0, a, 0, 0, 0);
        a = __builtin_amdgcn_mfma_f32_16x16x32_bf16(Dl1, bh1, a, 0, 0, 0);
#pragma unroll
        for (int r4 = 0; r4 < 4; ++r4)
            tld[(quad * 4 + r4) * 68 + nt * 16 + m16] = silu_f(a[r4] + db1v[nt]);
    }
    __syncthreads();
    // ---- decoder layer 2 + mask + pool ----
    float a3[16];
    *(float4*)&a3[0]  = *(const float4*)&tld[m16 * 68 + quad * 8 + 0];
    *(float4*)&a3[4]  = *(const float4*)&tld[m16 * 68 + quad * 8 + 4];
    *(float4*)&a3[8]  = *(const float4*)&tld[m16 * 68 + quad * 8 + 32];
    *(float4*)&a3[12] = *(const float4*)&tld[m16 * 68 + quad * 8 + 36];
    short8 Eh0, Eh1, El0, El1;
#pragma unroll
    for (int j = 0; j < 8; ++j) {
        unsigned short hi, lo;
        splitbf_t(a3[j], hi, lo);     Eh0[j] = (short)hi; El0[j] = (short)lo;
        splitbf_t(a3[8+j], hi, lo);   Eh1[j] = (short)hi; El1[j] = (short)lo;
    }
#pragma unroll
    for (int nt = 0; nt < 4; ++nt) {
        short8 bh0 = *(const short8*)(wD2 + ((nt*2+0) * 64 + lane) * 8);
        short8 bh1 = *(const short8*)(wD2 + ((nt*2+1) * 64 + lane) * 8);
        short8 bl0 = *(const short8*)(wD2 + 4096 + ((nt*2+0) * 64 + lane) * 8);
        short8 bl1 = *(const short8*)(wD2 + 4096 + ((nt*2+1) * 64 + lane) * 8);
        f32x4 a = {0.0f, 0.0f, 0.0f, 0.0f};
        a = __builtin_amdgcn_mfma_f32_16x16x32_bf16(Eh0, bh0, a, 0, 0, 0);
        a = __builtin_amdgcn_mfma_f32_16x16x32_bf16(Eh1, bh1, a, 0, 0, 0);
        a = __builtin_amdgcn_mfma_f32_16x16x32_bf16(Eh0, bl0, a, 0, 0, 0);
        a = __builtin_amdgcn_mfma_f32_16x16x32_bf16(Eh1, bl1, a, 0, 0, 0);
        a = __builtin_amdgcn_mfma_f32_16x16x32_bf16(El0, bh0, a, 0, 0, 0);
        a = __builtin_amdgcn_mfma_f32_16x16x32_bf16(El1, bh1, a, 0, 0, 0);
        float s = 0.0f;
#pragma unroll
        for (int r4 = 0; r4 < 4; ++r4)
            s += (a[r4] + db2v[nt]) * nm[r4];
        s += __shfl_xor(s, 16);
        s += __shfl_xor(s, 32);
        if (quad == 0) hgs[nt * 16 + m16] = s;
    }
    __syncthreads();
    // ---- graph decoder + reaction aggregation ----
    float acc = gb1[lane];
#pragma unroll
    for (int k = 0; k < H; ++k)
        acc += hgs[k] * gW1[k * H + lane];
    float part = silu_f(acc) * gW2[lane];
#pragma unroll
    for (int off = 32; off > 0; off >>= 1)
        part += __shfl_down(part, off);
    if (lane == 0)
        atomAddF(&pred[rid[blockIdx.x]], (part + gb2[0]) * rsign[blockIdx.x]);
}

extern "C" void kernel_launch(void* const* d_in, const int* in_sizes, int n_in,
                              void* d_out, int out_size, void* d_ws, size_t ws_size,
                              hipStream_t stream) {
    const float* h0      = (const float*)d_in[0];
    const float* pos     = (const float*)d_in[1];
    const int*   edges   = (const int*)d_in[2];
    const float* nmask   = (const float*)d_in[3];
    const float* emask   = (const float*)d_in[4];
    const int*   rid     = (const int*)d_in[5];
    const float* rsign   = (const float*)d_in[6];
    const float* emb_w   = (const float*)d_in[7];
    const float* emb_b   = (const float*)d_in[8];
    const float* edge_w1 = (const float*)d_in[9];
    const float* edge_b1 = (const float*)d_in[10];
    const float* edge_w2 = (const float*)d_in[11];
    const float* edge_b2 = (const float*)d_in[12];
    const float* node_w1 = (const float*)d_in[13];
    const float* node_b1 = (const float*)d_in[14];
    const float* node_w2 = (const float*)d_in[15];
    const float* node_b2 = (const float*)d_in[16];
    const float* dec_w1  = (const float*)d_in[17];
    const float* dec_b1  = (const float*)d_in[18];
    const float* dec_w2  = (const float*)d_in[19];
    const float* dec_b2  = (const float*)d_in[20];
    const float* g_w1    = (const float*)d_in[21];
    const float* g_b1    = (const float*)d_in[22];
    const float* g_w2    = (const float*)d_in[23];
    const float* g_b2    = (const float*)d_in[24];

    float* h      = (float*)d_ws;            // N*H
    float* agg    = h + N_NODES * H;         // N*H
    float* PA     = agg + N_NODES * H;       // N*H
    float* PB     = PA + N_NODES * H;        // N*H
    float4* csrQ  = (float4*)(PB + N_NODES * H);   // E float4 (16B aligned)
    int*   deg    = (int*)(csrQ + N_EDGES);  // N
    int*   off    = deg + N_NODES;           // N
    int*   bsum   = off + N_NODES;           // 256
    int*   bbase  = bsum + 256;              // 256
    int*   nstart = bbase + 256;             // N+1
    int*   cursor = nstart + N_NODES + 1;    // N
    short* wsW    = (short*)((((uintptr_t)(cursor + N_NODES)) + 255) & ~(uintptr_t)255);
    float* pred   = (float*)d_out;

    hipMemsetAsync(d_out, 0, R_REACT * sizeof(float), stream);
    hipMemsetAsync(deg, 0, N_NODES * sizeof(int), stream);

    k_prepw<<<228, 64, 0, stream>>>(edge_w1, edge_w2, node_w1, node_w2,
                                    dec_w1, dec_w2, emb_w, wsW);
    k_hist<<<N_EDGES / 256, 256, 0, stream>>>(edges, deg);
    k_scan_blk<<<256, 128, 0, stream>>>(deg, off, bsum);
    k_scan_top<<<1, 256, 0, stream>>>(bsum, bbase);
    k_cursor<<<N_NODES / 256, 256, 0, stream>>>(off, bbase, nstart, cursor);
    k_fill<<<N_EDGES / 256, 256, 0, stream>>>(edges, pos, emask, cursor, csrQ);
    k_embed_proj<<<N_NODES / 16, 64, 0, stream>>>(
        h0, wsW + WEMB, emb_b, wsW + WPROJ, edge_b1, h, PA, PB);

    for (int i = 0; i < L_LAYERS; ++i) {
        k_edge6<<<N_NODES / NPBLK, 256, 0, stream>>>(
            PA, PB, nstart, csrQ,
            edge_w1 + i * EIN * H,
            wsW + WE2 + i * 8192, edge_b2 + i * H, agg);
        if (i < L_LAYERS - 1) {
            k_node_proj<<<N_NODES / 16, 64, 0, stream>>>(
                h, agg, h0,
                wsW + WN1 + i * 20480, node_b1 + i * H,
                wsW + WN2 + i * 8192,  node_b2 + i * H,
                wsW + WPROJ + (i + 1) * 16384, edge_b1 + (i + 1) * H,
                PA, PB);
        } else {
            k_node_dec_graph<<<N_NODES / 16, 64, 0, stream>>>(
                h, agg, h0,
                wsW + WN1 + i * 20480, node_b1 + i * H,
                wsW + WN2 + i * 8192,  node_b2 + i * H,
                wsW + WD1, dec_b1, wsW + WD2, dec_b2,
                nmask, g_w1, g_b1, g_w2, g_b2, rid, rsign, pred);
        }
    }
}

// Round 13
// 476.830 us; speedup vs baseline: 1.0737x; 1.0124x over previous
//
#include <hip/hip_runtime.h>
#include <math.h>
#include <stdint.h>

#define N_NODES 32768
#define N_EDGES 491520
#define F_IN    11
#define H       64
#define G_GRAPHS 2048
#define NN_PER_G 16
#define R_REACT 1024
#define L_LAYERS 4
#define EIN     129   // 2H+1
#define NIN     139   // 2H+F
#define NPBLK   64    // nodes per k_edge6 block (R13: 32 -> 64, amortize prologue)

// preconverted-weight workspace layout (in shorts)
#define WPROJ 0                 // 4 layers x 16384 (16 frags hi @0, lo @8192)
#define WE2   65536             // 4 layers x 8192  (8 frags hi @0, lo @4096)
#define WN1   98304             // 4 layers x 20480 (20 frags hi @0, lo @10240)
#define WN2   180224            // 4 layers x 8192
#define WD1   212992            // 8192
#define WD2   221184            // 8192
#define WEMB  229376            // 4096 (4 frags hi @0, lo @2048)
#define WTOT  233472

typedef __attribute__((ext_vector_type(8))) short short8;
typedef __attribute__((ext_vector_type(4))) float f32x4;

__device__ __forceinline__ float silu_f(float x) {
    return x * __builtin_amdgcn_rcpf(1.0f + __expf(-x));
}
__device__ __forceinline__ void atomAddF(float* p, float v) {
    unsafeAtomicAdd(p, v);
}
__device__ __forceinline__ float bf2f(unsigned short b) {
    union { float f; unsigned u; } v; v.u = ((unsigned)b) << 16;
    return v.f;
}
__device__ __forceinline__ unsigned short f2bf(float x) {   // RNE
    union { float f; unsigned u; } v; v.f = x;
    unsigned r = v.u + 0x7FFFu + ((v.u >> 16) & 1u);
    return (unsigned short)(r >> 16);
}
// RNE split (weights, cold path)
__device__ __forceinline__ void splitbf(float x, unsigned short& hi, unsigned short& lo) {
    hi = f2bf(x);
    lo = f2bf(x - bf2f(hi));
}
// truncation split (hot path; validated absmax 3e-5)
__device__ __forceinline__ void splitbf_t(float x, unsigned short& hi, unsigned short& lo) {
    union { float f; unsigned u; } v; v.f = x;
    hi = (unsigned short)(v.u >> 16);
    union { float f; unsigned u; } w; w.f = x - bf2f(hi);
    lo = (unsigned short)(w.u >> 16);
}

// ---------------- weight fragment pre-conversion (runs once/call) --------
__global__ __launch_bounds__(64) void k_prepw(
        const float* __restrict__ ew1, const float* __restrict__ ew2,
        const float* __restrict__ nw1, const float* __restrict__ nw2,
        const float* __restrict__ dw1, const float* __restrict__ dw2,
        const float* __restrict__ embw,
        short* __restrict__ wsW) {
    const int b = blockIdx.x;
    const int lane = threadIdx.x;
    const int quad = lane >> 4, m16 = lane & 15;
    short8 h8, l8;
    short* base; int fidx, half;

    if (b < 64) {                       // edge_w1 rows 0..127 (proj)
        int l = b >> 4, f = b & 15;
        int nt = f >> 1, kf = f & 1;
#pragma unroll
        for (int j = 0; j < 8; ++j) {
            int row = (nt >= 4 ? 64 : 0) + kf * 32 + quad * 8 + j;
            unsigned short hi, lo;
            splitbf(ew1[l * EIN * H + row * H + (nt & 3) * 16 + m16], hi, lo);
            h8[j] = (short)hi; l8[j] = (short)lo;
        }
        base = wsW + WPROJ + l * 16384; fidx = f; half = 8192;
    } else if (b < 96) {                // edge_w2
        int bb = b - 64; int l = bb >> 3, f = bb & 7;
        int nt = f >> 1, kf = f & 1;
#pragma unroll
        for (int j = 0; j < 8; ++j) {
            int row = kf * 32 + quad * 8 + j;
            unsigned short hi, lo;
            splitbf(ew2[l * H * H + row * H + nt * 16 + m16], hi, lo);
            h8[j] = (short)hi; l8[j] = (short)lo;
        }
        base = wsW + WE2 + l * 8192; fidx = f; half = 4096;
    } else if (b < 176) {               // node_w1 (rows padded to 160)
        int bb = b - 96; int l = bb / 20, f = bb % 20;
        int nt = f / 5, kf = f % 5;
#pragma unroll
        for (int j = 0; j < 8; ++j) {
            int row = kf * 32 + quad * 8 + j;
            float w = (row < NIN) ? nw1[l * NIN * H + row * H + nt * 16 + m16] : 0.0f;
            unsigned short hi, lo; splitbf(w, hi, lo);
            h8[j] = (short)hi; l8[j] = (short)lo;
        }
        base = wsW + WN1 + l * 20480; fidx = f; half = 10240;
    } else if (b < 208) {               // node_w2
        int bb = b - 176; int l = bb >> 3, f = bb & 7;
        int nt = f >> 1, kf = f & 1;
#pragma unroll
        for (int j = 0; j < 8; ++j) {
            int row = kf * 32 + quad * 8 + j;
            unsigned short hi, lo;
            splitbf(nw2[l * H * H + row * H + nt * 16 + m16], hi, lo);
            h8[j] = (short)hi; l8[j] = (short)lo;
        }
        base = wsW + WN2 + l * 8192; fidx = f; half = 4096;
    } else if (b < 216) {               // dec_w1
        int f = b - 208;
        int nt = f >> 1, kf = f & 1;
#pragma unroll
        for (int j = 0; j < 8; ++j) {
            int row = kf * 32 + quad * 8 + j;
            unsigned short hi, lo;
            splitbf(dw1[row * H + nt * 16 + m16], hi, lo);
            h8[j] = (short)hi; l8[j] = (short)lo;
        }
        base = wsW + WD1; fidx = f; half = 4096;
    } else if (b < 224) {               // dec_w2
        int f = b - 216;
        int nt = f >> 1, kf = f & 1;
#pragma unroll
        for (int j = 0; j < 8; ++j) {
            int row = kf * 32 + quad * 8 + j;
            unsigned short hi, lo;
            splitbf(dw2[row * H + nt * 16 + m16], hi, lo);
            h8[j] = (short)hi; l8[j] = (short)lo;
        }
        base = wsW + WD2; fidx = f; half = 4096;
    } else {                            // emb_w (K=32 frag, rows >= F_IN zero)
        int f = b - 224;                // = nt
#pragma unroll
        for (int j = 0; j < 8; ++j) {
            int row = quad * 8 + j;
            float w = (row < F_IN) ? embw[row * H + f * 16 + m16] : 0.0f;
            unsigned short hi, lo; splitbf(w, hi, lo);
            h8[j] = (short)hi; l8[j] = (short)lo;
        }
        base = wsW + WEMB; fidx = f; half = 2048;
    }
    *(short8*)(base + (fidx * 64 + lane) * 8) = h8;
    *(short8*)(base + half + (fidx * 64 + lane) * 8) = l8;
}

// ---------------- CSR build ----------------
__global__ __launch_bounds__(256) void k_hist(
        const int* __restrict__ edges, int* __restrict__ deg) {
    int e = blockIdx.x * 256 + threadIdx.x;
    atomicAdd(&deg[edges[e]], 1);
}

__global__ __launch_bounds__(128) void k_scan_blk(
        const int* __restrict__ deg, int* __restrict__ off,
        int* __restrict__ bsum) {
    __shared__ int sd[128];
    int b = blockIdx.x;
    sd[threadIdx.x] = deg[b * 128 + threadIdx.x];
    __syncthreads();
    if (threadIdx.x == 0) {
        int s = 0;
        for (int i = 0; i < 128; ++i) { int d = sd[i]; sd[i] = s; s += d; }
        bsum[b] = s;
    }
    __syncthreads();
    off[b * 128 + threadIdx.x] = sd[threadIdx.x];
}

__global__ __launch_bounds__(256) void k_scan_top(
        const int* __restrict__ bsum, int* __restrict__ bbase) {
    __shared__ int sb[256];
    sb[threadIdx.x] = bsum[threadIdx.x];
    __syncthreads();
    if (threadIdx.x == 0) {
        int s = 0;
        for (int i = 0; i < 256; ++i) { int d = sb[i]; sb[i] = s; s += d; }
    }
    __syncthreads();
    bbase[threadIdx.x] = sb[threadIdx.x];
}

__global__ __launch_bounds__(256) void k_cursor(
        const int* __restrict__ off, const int* __restrict__ bbase,
        int* __restrict__ nstart, int* __restrict__ cursor) {
    int n = blockIdx.x * 256 + threadIdx.x;
    int ns = off[n] + bbase[n >> 7];
    nstart[n] = ns;
    cursor[n] = ns;
    if (n == 0) nstart[N_NODES] = N_EDGES;
}

// fill: radial fused + PACKED meta (one float4/edge: {pk, rad, mask, 0})
__global__ __launch_bounds__(256) void k_fill(
        const int* __restrict__ edges, const float* __restrict__ posi,
        const float* __restrict__ emask, int* __restrict__ cursor,
        float4* __restrict__ csrQ) {
    int e = blockIdx.x * 256 + threadIdx.x;
    int r = edges[e], c = edges[N_EDGES + e];
    float dx = posi[r * 3 + 0] - posi[c * 3 + 0];
    float dy = posi[r * 3 + 1] - posi[c * 3 + 1];
    float dz = posi[r * 3 + 2] - posi[c * 3 + 2];
    float rad = dx * dx + dy * dy + dz * dz;
    int p = atomicAdd(&cursor[r], 1);
    int pk = c | ((r & (NPBLK - 1)) << 16);  // col | row_local
    csrQ[p] = make_float4(__int_as_float(pk), rad, emask[e], 0.0f);
}

// ---------------- embed + layer-0 projection (fused) ---------------------
__global__ __launch_bounds__(64, 2) void k_embed_proj(
        const float* __restrict__ h0, const short* __restrict__ wEmb,
        const float* __restrict__ emb_b,
        const short* __restrict__ wP, const float* __restrict__ eb1,
        float* __restrict__ h, float* __restrict__ PA, float* __restrict__ PB) {
    const int lane = threadIdx.x;
    const int quad = lane >> 4, m16 = lane & 15;
    const int nb = blockIdx.x * 16;
    __shared__ float tld[16 * 68];

    float a0[8];
    const float* h0p = h0 + (nb + m16) * F_IN;
#pragma unroll
    for (int j = 0; j < 8; ++j) {
        int kk = quad * 8 + j;
        a0[j] = (kk < F_IN) ? h0p[kk] : 0.0f;
    }
    short8 A0h, A0l;
#pragma unroll
    for (int j = 0; j < 8; ++j) {
        unsigned short hi, lo; splitbf_t(a0[j], hi, lo);
        A0h[j] = (short)hi; A0l[j] = (short)lo;
    }
    float ebv[4];
#pragma unroll
    for (int nt = 0; nt < 4; ++nt) ebv[nt] = emb_b[nt * 16 + m16];

#pragma unroll
    for (int nt = 0; nt < 4; ++nt) {
        short8 bh = *(const short8*)(wEmb + (nt * 64 + lane) * 8);
        short8 bl = *(const short8*)(wEmb + 2048 + (nt * 64 + lane) * 8);
        f32x4 a = {0.0f, 0.0f, 0.0f, 0.0f};
        a = __builtin_amdgcn_mfma_f32_16x16x32_bf16(A0h, bh, a, 0, 0, 0);
        a = __builtin_amdgcn_mfma_f32_16x16x32_bf16(A0h, bl, a, 0, 0, 0);
        a = __builtin_amdgcn_mfma_f32_16x16x32_bf16(A0l, bh, a, 0, 0, 0);
#pragma unroll
        for (int r4 = 0; r4 < 4; ++r4) {
            const int node = nb + quad * 4 + r4;
            float hv = a[r4] + ebv[nt];
            h[node * H + nt * 16 + m16] = hv;
            tld[(quad * 4 + r4) * 68 + nt * 16 + m16] = hv;
        }
    }
    __syncthreads();
    float av[16];
    *(float4*)&av[0]  = *(const float4*)&tld[m16 * 68 + quad * 8 + 0];
    *(float4*)&av[4]  = *(const float4*)&tld[m16 * 68 + quad * 8 + 4];
    *(float4*)&av[8]  = *(const float4*)&tld[m16 * 68 + quad * 8 + 32];
    *(float4*)&av[12] = *(const float4*)&tld[m16 * 68 + quad * 8 + 36];
    short8 Ah0, Ah1, Al0, Al1;
#pragma unroll
    for (int j = 0; j < 8; ++j) {
        unsigned short hi, lo;
        splitbf_t(av[j], hi, lo);     Ah0[j] = (short)hi; Al0[j] = (short)lo;
        splitbf_t(av[8 + j], hi, lo); Ah1[j] = (short)hi; Al1[j] = (short)lo;
    }
    float b1v[4];
#pragma unroll
    for (int nt = 0; nt < 4; ++nt) b1v[nt] = eb1[nt * 16 + m16];
#pragma unroll
    for (int nt = 0; nt < 8; ++nt) {
        short8 bh0 = *(const short8*)(wP + ((nt*2+0) * 64 + lane) * 8);
        short8 bh1 = *(const short8*)(wP + ((nt*2+1) * 64 + lane) * 8);
        short8 bl0 = *(const short8*)(wP + 8192 + ((nt*2+0) * 64 + lane) * 8);
        short8 bl1 = *(const short8*)(wP + 8192 + ((nt*2+1) * 64 + lane) * 8);
        f32x4 a = {0.0f, 0.0f, 0.0f, 0.0f};
        a = __builtin_amdgcn_mfma_f32_16x16x32_bf16(Ah0, bh0, a, 0, 0, 0);
        a = __builtin_amdgcn_mfma_f32_16x16x32_bf16(Ah1, bh1, a, 0, 0, 0);
        a = __builtin_amdgcn_mfma_f32_16x16x32_bf16(Ah0, bl0, a, 0, 0, 0);
        a = __builtin_amdgcn_mfma_f32_16x16x32_bf16(Ah1, bl1, a, 0, 0, 0);
        a = __builtin_amdgcn_mfma_f32_16x16x32_bf16(Al0, bh0, a, 0, 0, 0);
        a = __builtin_amdgcn_mfma_f32_16x16x32_bf16(Al1, bh1, a, 0, 0, 0);
#pragma unroll
        for (int r4 = 0; r4 < 4; ++r4) {
            const int node = nb + quad * 4 + r4;
            if (nt < 4)
                PA[node * H + nt * 16 + m16] = a[r4] + b1v[nt];
            else
                PB[node * H + (nt - 4) * 16 + m16] = a[r4];
        }
    }
}

// ------ edge MLP: R7 structure, NPBLK=64 (prologue amortization) ---------
__global__ __launch_bounds__(256, 2) void k_edge6(
        const float* __restrict__ PA, const float* __restrict__ PB,
        const int* __restrict__ nstart, const float4* __restrict__ csrQ,
        const float* __restrict__ W1,   // only row 128 (w1c) used
        const short* __restrict__ wE2, const float* __restrict__ b2,
        float* __restrict__ agg) {
    const int tid = threadIdx.x;
    const int lane = tid & 63, wave = tid >> 6;
    const int quad = lane >> 4, m16 = lane & 15;
    const int n0 = blockIdx.x * NPBLK;

    __shared__ float aggld[NPBLK * 68];
    for (int i = tid; i < NPBLK * 68; i += 256) aggld[i] = 0.0f;

    short8 Bh[8], Bl[8];
#pragma unroll
    for (int f = 0; f < 8; ++f) {
        Bh[f] = *(const short8*)(wE2 + (f * 64 + lane) * 8);
        Bl[f] = *(const short8*)(wE2 + 4096 + (f * 64 + lane) * 8);
    }
    float w1cr[16];
#pragma unroll
    for (int i = 0; i < 16; ++i) {
        int k = (i < 8) ? (quad * 8 + i) : (32 + quad * 8 + (i - 8));
        w1cr[i] = W1[128 * H + k];
    }
    float b2v[4];
#pragma unroll
    for (int nt = 0; nt < 4; ++nt) b2v[nt] = b2[nt * 16 + m16];

    const int start = nstart[n0];
    const int end   = nstart[n0 + NPBLK];
    __syncthreads();

    const int ntiles = (end - start + 15) >> 4;

    // A: data fully resident; B: meta resident, bv gather at loop top;
    // C: meta loads in flight during compute.
    int   pkA = 0, pkB = 0;
    float radA = 0.0f, radB = 0.0f;
    float avA[16], bvA[16];

    int tA = wave;
    bool haveA = tA < ntiles;
    if (haveA) {
        const int idx = start + tA * 16 + m16;
        const int ss  = min(idx, N_EDGES - 1);
        float4 q = csrQ[ss];
        pkA  = __float_as_int(q.x);
        radA = q.y;
        const int c  = pkA & 0xFFFF;
        const int rl = pkA >> 16;
        const float* par = PA + (n0 + rl) * H + quad * 8;
        const float* pbr = PB + c * H + quad * 8;
        *(float4*)&avA[0]  = *(const float4*)(par + 0);
        *(float4*)&avA[4]  = *(const float4*)(par + 4);
        *(float4*)&avA[8]  = *(const float4*)(par + 32);
        *(float4*)&avA[12] = *(const float4*)(par + 36);
        *(float4*)&bvA[0]  = *(const float4*)(pbr + 0);
        *(float4*)&bvA[4]  = *(const float4*)(pbr + 4);
        *(float4*)&bvA[8]  = *(const float4*)(pbr + 32);
        *(float4*)&bvA[12] = *(const float4*)(pbr + 36);
    }
    int tB = tA + 4;
    bool haveB = tB < ntiles;
    if (haveB) {
        const int idx = start + tB * 16 + m16;
        const int ss  = min(idx, N_EDGES - 1);
        float4 q = csrQ[ss];
        pkB  = __float_as_int(q.x);
        radB = q.y;
    }

    while (haveA) {
        // 1. gather B data (meta already resident)
        float bvB[16];
        if (haveB) {
            const int c = pkB & 0xFFFF;
            const float* pbr = PB + c * H + quad * 8;
            *(float4*)&bvB[0]  = *(const float4*)(pbr + 0);
            *(float4*)&bvB[4]  = *(const float4*)(pbr + 4);
            *(float4*)&bvB[8]  = *(const float4*)(pbr + 32);
            *(float4*)&bvB[12] = *(const float4*)(pbr + 36);
        }
        // 2. issue meta load for C (packed: one float4)
        const int tC = tB + 4;
        const bool haveC = tC < ntiles;
        int pkC = 0; float radC = 0.0f;
        if (haveC) {
            const int idx = start + tC * 16 + m16;
            const int ss  = min(idx, N_EDGES - 1);
            float4 q = csrQ[ss];
            pkC  = __float_as_int(q.x);
            radC = q.y;
        }
        // 3. per-quad meta for tile A (packed: 4 float4 loads, L1-warm)
        int rlq[4]; float mkq[4];
        const int sb = start + tA * 16 + quad * 4;
#pragma unroll
        for (int r4 = 0; r4 < 4; ++r4) {
            int s = sb + r4, s2 = min(s, N_EDGES - 1);
            float4 q = csrQ[s2];
            rlq[r4] = __float_as_int(q.x) >> 16;
            mkq[r4] = (s < end) ? q.z : 0.0f;
        }

        // 4. compute tile A
        short8 Ah0, Ah1, Al0, Al1;
#pragma unroll
        for (int i = 0; i < 8; ++i) {
            unsigned short hi, lo;
            splitbf_t(silu_f(avA[i] + bvA[i] + radA * w1cr[i]), hi, lo);
            Ah0[i] = (short)hi; Al0[i] = (short)lo;
            splitbf_t(silu_f(avA[8+i] + bvA[8+i] + radA * w1cr[8+i]), hi, lo);
            Ah1[i] = (short)hi; Al1[i] = (short)lo;
        }
        f32x4 acc[4];
#pragma unroll
        for (int nt = 0; nt < 4; ++nt) {
            f32x4 a = {0.0f, 0.0f, 0.0f, 0.0f};
            a = __builtin_amdgcn_mfma_f32_16x16x32_bf16(Ah0, Bh[nt*2+0], a, 0, 0, 0);
            a = __builtin_amdgcn_mfma_f32_16x16x32_bf16(Ah1, Bh[nt*2+1], a, 0, 0, 0);
            a = __builtin_amdgcn_mfma_f32_16x16x32_bf16(Ah0, Bl[nt*2+0], a, 0, 0, 0);
            a = __builtin_amdgcn_mfma_f32_16x16x32_bf16(Ah1, Bl[nt*2+1], a, 0, 0, 0);
            a = __builtin_amdgcn_mfma_f32_16x16x32_bf16(Al0, Bh[nt*2+0], a, 0, 0, 0);
            a = __builtin_amdgcn_mfma_f32_16x16x32_bf16(Al1, Bh[nt*2+1], a, 0, 0, 0);
            acc[nt] = a;
        }

        // 5. epilogue: run-reduced LDS atomics
#pragma unroll
        for (int nt = 0; nt < 4; ++nt) {
            float oo[4];
#pragma unroll
            for (int r4 = 0; r4 < 4; ++r4)
                oo[r4] = silu_f(acc[nt][r4] + b2v[nt]) * mkq[r4];
            int cur = rlq[0]; float s = oo[0];
#pragma unroll
            for (int r4 = 1; r4 < 4; ++r4) {
                if (rlq[r4] == cur) { s += oo[r4]; }
                else {
                    atomicAdd(&aggld[cur * 68 + nt * 16 + m16], s);
                    cur = rlq[r4]; s = oo[r4];
                }
            }
            atomicAdd(&aggld[cur * 68 + nt * 16 + m16], s);
        }

        // 6. shift pipeline (avA reload is L1-hot; late is fine — R2/R6 A/B)
        if (haveB) {
            const int rl = pkB >> 16;
            const float* par = PA + (n0 + rl) * H + quad * 8;
            *(float4*)&avA[0]  = *(const float4*)(par + 0);
            *(float4*)&avA[4]  = *(const float4*)(par + 4);
            *(float4*)&avA[8]  = *(const float4*)(par + 32);
            *(float4*)&avA[12] = *(const float4*)(par + 36);
#pragma unroll
            for (int i = 0; i < 16; ++i) bvA[i] = bvB[i];
            pkA = pkB; radA = radB;
        }
        pkB = pkC; radB = radC;
        tA = tB; tB = tC; haveA = haveB; haveB = haveC;
    }

    __syncthreads();
#pragma unroll
    for (int i = tid; i < NPBLK * 16; i += 256) {
        int n = i >> 4, cb = (i & 15) << 2;
        *(float4*)&agg[(n0 + n) * H + cb] = *(const float4*)&aggld[n * 68 + cb];
    }
}

// ---------------- node MLP + next-layer projection (fused) ---------------
__global__ __launch_bounds__(64, 2) void k_node_proj(
        float* __restrict__ h, const float* __restrict__ agg,
        const float* __restrict__ h0,
        const short* __restrict__ wN1, const float* __restrict__ b1,
        const short* __restrict__ wN2, const float* __restrict__ b2,
        const short* __restrict__ wPn, const float* __restrict__ eb1n,
        float* __restrict__ PA, float* __restrict__ PB) {
    const int lane = threadIdx.x;
    const int quad = lane >> 4, m16 = lane & 15;
    const int nb = blockIdx.x * 16;

    float b1v[4], b2v[4];
#pragma unroll
    for (int nt = 0; nt < 4; ++nt) {
        b1v[nt] = b1[nt * 16 + m16];
        b2v[nt] = b2[nt * 16 + m16];
    }
    __shared__ float tld[16 * 68];

    // ---- node MLP layer 1 ----
    float a1[5][8];
    const float* hp = h + (nb + m16) * H + quad * 8;
    const float* ap = agg + (nb + m16) * H + quad * 8;
    *(float4*)&a1[0][0] = *(const float4*)(hp + 0);
    *(float4*)&a1[0][4] = *(const float4*)(hp + 4);
    *(float4*)&a1[1][0] = *(const float4*)(hp + 32);
    *(float4*)&a1[1][4] = *(const float4*)(hp + 36);
    *(float4*)&a1[2][0] = *(const float4*)(ap + 0);
    *(float4*)&a1[2][4] = *(const float4*)(ap + 4);
    *(float4*)&a1[3][0] = *(const float4*)(ap + 32);
    *(float4*)&a1[3][4] = *(const float4*)(ap + 36);
    const float* h0p = h0 + (nb + m16) * F_IN;
#pragma unroll
    for (int j = 0; j < 8; ++j) {
        int kk = quad * 8 + j;
        a1[4][j] = (kk < F_IN) ? h0p[kk] : 0.0f;
    }
    short8 A1h[5], A1l[5];
#pragma unroll
    for (int kf = 0; kf < 5; ++kf) {
        short8 ah, al;
#pragma unroll
        for (int j = 0; j < 8; ++j) {
            unsigned short hi, lo; splitbf_t(a1[kf][j], hi, lo);
            ah[j] = (short)hi; al[j] = (short)lo;
        }
        A1h[kf] = ah; A1l[kf] = al;
    }
#pragma unroll
    for (int nt = 0; nt < 4; ++nt) {
        short8 bh[5], bl[5];
#pragma unroll
        for (int kf = 0; kf < 5; ++kf) {
            bh[kf] = *(const short8*)(wN1 + ((nt*5+kf) * 64 + lane) * 8);
            bl[kf] = *(const short8*)(wN1 + 10240 + ((nt*5+kf) * 64 + lane) * 8);
        }
        f32x4 a = {0.0f, 0.0f, 0.0f, 0.0f};
#pragma unroll
        for (int kf = 0; kf < 5; ++kf)
            a = __builtin_amdgcn_mfma_f32_16x16x32_bf16(A1h[kf], bh[kf], a, 0, 0, 0);
#pragma unroll
        for (int kf = 0; kf < 5; ++kf)
            a = __builtin_amdgcn_mfma_f32_16x16x32_bf16(A1h[kf], bl[kf], a, 0, 0, 0);
#pragma unroll
        for (int kf = 0; kf < 5; ++kf)
            a = __builtin_amdgcn_mfma_f32_16x16x32_bf16(A1l[kf], bh[kf], a, 0, 0, 0);
#pragma unroll
        for (int r4 = 0; r4 < 4; ++r4)
            tld[(quad * 4 + r4) * 68 + nt * 16 + m16] = silu_f(a[r4] + b1v[nt]);
    }
    __syncthreads();
    // ---- node MLP layer 2 ----
    float a2[16];
    *(float4*)&a2[0]  = *(const float4*)&tld[m16 * 68 + quad * 8 + 0];
    *(float4*)&a2[4]  = *(const float4*)&tld[m16 * 68 + quad * 8 + 4];
    *(float4*)&a2[8]  = *(const float4*)&tld[m16 * 68 + quad * 8 + 32];
    *(float4*)&a2[12] = *(const float4*)&tld[m16 * 68 + quad * 8 + 36];
    short8 A2h0, A2h1, A2l0, A2l1;
#pragma unroll
    for (int j = 0; j < 8; ++j) {
        unsigned short hi, lo;
        splitbf_t(a2[j], hi, lo);     A2h0[j] = (short)hi; A2l0[j] = (short)lo;
        splitbf_t(a2[8+j], hi, lo);   A2h1[j] = (short)hi; A2l1[j] = (short)lo;
    }
    __syncthreads();   // a2 reads complete before tld overwritten
#pragma unroll
    for (int nt = 0; nt < 4; ++nt) {
        short8 bh0 = *(const short8*)(wN2 + ((nt*2+0) * 64 + lane) * 8);
        short8 bh1 = *(const short8*)(wN2 + ((nt*2+1) * 64 + lane) * 8);
        short8 bl0 = *(const short8*)(wN2 + 4096 + ((nt*2+0) * 64 + lane) * 8);
        short8 bl1 = *(const short8*)(wN2 + 4096 + ((nt*2+1) * 64 + lane) * 8);
        f32x4 a = {0.0f, 0.0f, 0.0f, 0.0f};
        a = __builtin_amdgcn_mfma_f32_16x16x32_bf16(A2h0, bh0, a, 0, 0, 0);
        a = __builtin_amdgcn_mfma_f32_16x16x32_bf16(A2h1, bh1, a, 0, 0, 0);
        a = __builtin_amdgcn_mfma_f32_16x16x32_bf16(A2h0, bl0, a, 0, 0, 0);
        a = __builtin_amdgcn_mfma_f32_16x16x32_bf16(A2h1, bl1, a, 0, 0, 0);
        a = __builtin_amdgcn_mfma_f32_16x16x32_bf16(A2l0, bh0, a, 0, 0, 0);
        a = __builtin_amdgcn_mfma_f32_16x16x32_bf16(A2l1, bh1, a, 0, 0, 0);
#pragma unroll
        for (int r4 = 0; r4 < 4; ++r4) {
            const int node = nb + quad * 4 + r4;
            float hv = a[r4] + b2v[nt];
            h[node * H + nt * 16 + m16] = hv;
            tld[(quad * 4 + r4) * 68 + nt * 16 + m16] = hv;
        }
    }
    __syncthreads();
    // ---- projection for next layer ----
    float av[16];
    *(float4*)&av[0]  = *(const float4*)&tld[m16 * 68 + quad * 8 + 0];
    *(float4*)&av[4]  = *(const float4*)&tld[m16 * 68 + quad * 8 + 4];
    *(float4*)&av[8]  = *(const float4*)&tld[m16 * 68 + quad * 8 + 32];
    *(float4*)&av[12] = *(const float4*)&tld[m16 * 68 + quad * 8 + 36];
    short8 Ph0, Ph1, Pl0, Pl1;
#pragma unroll
    for (int j = 0; j < 8; ++j) {
        unsigned short hi, lo;
        splitbf_t(av[j], hi, lo);     Ph0[j] = (short)hi; Pl0[j] = (short)lo;
        splitbf_t(av[8+j], hi, lo);   Ph1[j] = (short)hi; Pl1[j] = (short)lo;
    }
    float b1ev[4];
#pragma unroll
    for (int nt = 0; nt < 4; ++nt) b1ev[nt] = eb1n[nt * 16 + m16];
#pragma unroll
    for (int nt = 0; nt < 8; ++nt) {
        short8 bh0 = *(const short8*)(wPn + ((nt*2+0) * 64 + lane) * 8);
        short8 bh1 = *(const short8*)(wPn + ((nt*2+1) * 64 + lane) * 8);
        short8 bl0 = *(const short8*)(wPn + 8192 + ((nt*2+0) * 64 + lane) * 8);
        short8 bl1 = *(const short8*)(wPn + 8192 + ((nt*2+1) * 64 + lane) * 8);
        f32x4 a = {0.0f, 0.0f, 0.0f, 0.0f};
        a = __builtin_amdgcn_mfma_f32_16x16x32_bf16(Ph0, bh0, a, 0, 0, 0);
        a = __builtin_amdgcn_mfma_f32_16x16x32_bf16(Ph1, bh1, a, 0, 0, 0);
        a = __builtin_amdgcn_mfma_f32_16x16x32_bf16(Ph0, bl0, a, 0, 0, 0);
        a = __builtin_amdgcn_mfma_f32_16x16x32_bf16(Ph1, bl1, a, 0, 0, 0);
        a = __builtin_amdgcn_mfma_f32_16x16x32_bf16(Pl0, bh0, a, 0, 0, 0);
        a = __builtin_amdgcn_mfma_f32_16x16x32_bf16(Pl1, bh1, a, 0, 0, 0);
#pragma unroll
        for (int r4 = 0; r4 < 4; ++r4) {
            const int node = nb + quad * 4 + r4;
            if (nt < 4)
                PA[node * H + nt * 16 + m16] = a[r4] + b1ev[nt];
            else
                PB[node * H + (nt - 4) * 16 + m16] = a[r4];
        }
    }
}

// ------- layer-3 node MLP + node decoder + pool + graph dec + reaction ---
__global__ __launch_bounds__(64, 2) void k_node_dec_graph(
        const float* __restrict__ h, const float* __restrict__ agg,
        const float* __restrict__ h0,
        const short* __restrict__ wN1, const float* __restrict__ b1,
        const short* __restrict__ wN2, const float* __restrict__ b2,
        const short* __restrict__ wD1, const float* __restrict__ db1,
        const short* __restrict__ wD2, const float* __restrict__ db2,
        const float* __restrict__ nmask,
        const float* __restrict__ gW1, const float* __restrict__ gb1,
        const float* __restrict__ gW2, const float* __restrict__ gb2,
        const int* __restrict__ rid, const float* __restrict__ rsign,
        float* __restrict__ pred) {
    const int lane = threadIdx.x;
    const int quad = lane >> 4, m16 = lane & 15;
    const int nb = blockIdx.x * 16;

    float b1v[4], b2v[4], db1v[4], db2v[4];
#pragma unroll
    for (int nt = 0; nt < 4; ++nt) {
        b1v[nt]  = b1[nt * 16 + m16];
        b2v[nt]  = b2[nt * 16 + m16];
        db1v[nt] = db1[nt * 16 + m16];
        db2v[nt] = db2[nt * 16 + m16];
    }
    float nm[4];
#pragma unroll
    for (int r4 = 0; r4 < 4; ++r4) nm[r4] = nmask[nb + quad * 4 + r4];

    __shared__ float tld[16 * 68];
    __shared__ __align__(16) float hgs[64];

    // ---- node MLP layer 1 ----
    float a1[5][8];
    const float* hp = h + (nb + m16) * H + quad * 8;
    const float* ap = agg + (nb + m16) * H + quad * 8;
    *(float4*)&a1[0][0] = *(const float4*)(hp + 0);
    *(float4*)&a1[0][4] = *(const float4*)(hp + 4);
    *(float4*)&a1[1][0] = *(const float4*)(hp + 32);
    *(float4*)&a1[1][4] = *(const float4*)(hp + 36);
    *(float4*)&a1[2][0] = *(const float4*)(ap + 0);
    *(float4*)&a1[2][4] = *(const float4*)(ap + 4);
    *(float4*)&a1[3][0] = *(const float4*)(ap + 32);
    *(float4*)&a1[3][4] = *(const float4*)(ap + 36);
    const float* h0p = h0 + (nb + m16) * F_IN;
#pragma unroll
    for (int j = 0; j < 8; ++j) {
        int kk = quad * 8 + j;
        a1[4][j] = (kk < F_IN) ? h0p[kk] : 0.0f;
    }
    short8 A1h[5], A1l[5];
#pragma unroll
    for (int kf = 0; kf < 5; ++kf) {
        short8 ah, al;
#pragma unroll
        for (int j = 0; j < 8; ++j) {
            unsigned short hi, lo; splitbf_t(a1[kf][j], hi, lo);
            ah[j] = (short)hi; al[j] = (short)lo;
        }
        A1h[kf] = ah; A1l[kf] = al;
    }
#pragma unroll
    for (int nt = 0; nt < 4; ++nt) {
        short8 bh[5], bl[5];
#pragma unroll
        for (int kf = 0; kf < 5; ++kf) {
            bh[kf] = *(const short8*)(wN1 + ((nt*5+kf) * 64 + lane) * 8);
            bl[kf] = *(const short8*)(wN1 + 10240 + ((nt*5+kf) * 64 + lane) * 8);
        }
        f32x4 a = {0.0f, 0.0f, 0.0f, 0.0f};
#pragma unroll
        for (int kf = 0; kf < 5; ++kf)
            a = __builtin_amdgcn_mfma_f32_16x16x32_bf16(A1h[kf], bh[kf], a, 0, 0, 0);
#pragma unroll
        for (int kf = 0; kf < 5; ++kf)
            a = __builtin_amdgcn_mfma_f32_16x16x32_bf16(A1h[kf], bl[kf], a, 0, 0, 0);
#pragma unroll
        for (int kf = 0; kf < 5; ++kf)
            a = __builtin_amdgcn_mfma_f32_16x16x32_bf16(A1l[kf], bh[kf], a, 0, 0, 0);
#pragma unroll
        for (int r4 = 0; r4 < 4; ++r4)
            tld[(quad * 4 + r4) * 68 + nt * 16 + m16] = silu_f(a[r4] + b1v[nt]);
    }
    __syncthreads();
    // ---- node MLP layer 2 (h_new stays in LDS) ----
    float a2[16];
    *(float4*)&a2[0]  = *(const float4*)&tld[m16 * 68 + quad * 8 + 0];
    *(float4*)&a2[4]  = *(const float4*)&tld[m16 * 68 + quad * 8 + 4];
    *(float4*)&a2[8]  = *(const float4*)&tld[m16 * 68 + quad * 8 + 32];
    *(float4*)&a2[12] = *(const float4*)&tld[m16 * 68 + quad * 8 + 36];
    short8 A2h0, A2h1, A2l0, A2l1;
#pragma unroll
    for (int j = 0; j < 8; ++j) {
        unsigned short hi, lo;
        splitbf_t(a2[j], hi, lo);     A2h0[j] = (short)hi; A2l0[j] = (short)lo;
        splitbf_t(a2[8+j], hi, lo);   A2h1[j] = (short)hi; A2l1[j] = (short)lo;
    }
    __syncthreads();
#pragma unroll
    for (int nt = 0; nt < 4; ++nt) {
        short8 bh0 = *(const short8*)(wN2 + ((nt*2+0) * 64 + lane) * 8);
        short8 bh1 = *(const short8*)(wN2 + ((nt*2+1) * 64 + lane) * 8);
        short8 bl0 = *(const short8*)(wN2 + 4096 + ((nt*2+0) * 64 + lane) * 8);
        short8 bl1 = *(const short8*)(wN2 + 4096 + ((nt*2+1) * 64 + lane) * 8);
        f32x4 a = {0.0f, 0.0f, 0.0f, 0.0f};
        a = __builtin_amdgcn_mfma_f32_16x16x32_bf16(A2h0, bh0, a, 0, 0, 0);
        a = __builtin_amdgcn_mfma_f32_16x16x32_bf16(A2h1, bh1, a, 0, 0, 0);
        a = __builtin_amdgcn_mfma_f32_16x16x32_bf16(A2h0, bl0, a, 0, 0, 0);
        a = __builtin_amdgcn_mfma_f32_16x16x32_bf16(A2h1, bl1, a, 0, 0, 0);
        a = __builtin_amdgcn_mfma_f32_16x16x32_bf16(A2l0, bh0, a, 0, 0, 0);
        a = __builtin_amdgcn_mfma_f32_16x16x32_bf16(A2l1, bh1, a, 0, 0, 0);
#pragma unroll
        for (int r4 = 0; r4 < 4; ++r4)
            tld[(quad * 4 + r4) * 68 + nt * 16 + m16] = a[r4] + b2v[nt];
    }
    __syncthreads();
    // ---- decoder layer 1 ----
    float av[16];
    *(float4*)&av[0]  = *(const float4*)&tld[m16 * 68 + quad * 8 + 0];
    *(float4*)&av[4]  = *(const float4*)&tld[m16 * 68 + quad * 8 + 4];
    *(float4*)&av[8]  = *(const float4*)&tld[m16 * 68 + quad * 8 + 32];
    *(float4*)&av[12] = *(const float4*)&tld[m16 * 68 + quad * 8 + 36];
    short8 Dh0, Dh1, Dl0, Dl1;
#pragma unroll
    for (int j = 0; j < 8; ++j) {
        unsigned short hi, lo;
        splitbf_t(av[j], hi, lo);     Dh0[j] = (short)hi; Dl0[j] = (short)lo;
        splitbf_t(av[8+j], hi, lo);   Dh1[j] = (short)hi; Dl1[j] = (short)lo;
    }
    __syncthreads();
#pragma unroll
    for (int nt = 0; nt < 4; ++nt) {
        short8 bh0 = *(const short8*)(wD1 + ((nt*2+0) * 64 + lane) * 8);
        short8 bh1 = *(const short8*)(wD1 + ((nt*2+1) * 64 + lane) * 8);
        short8 bl0 = *(const short8*)(wD1 + 4096 + ((nt*2+0) * 64 + lane) * 8);
        short8 bl1 = *(const short8*)(wD1 + 4096 + ((nt*2+1) * 64 + lane) * 8);
        f32x4 a = {0.0f, 0.0f, 0.0f, 0.0f};
        a = __builtin_amdgcn_mfma_f32_16x16x32_bf16(Dh0, bh0, a, 0, 0, 0);
        a = __builtin_amdgcn_mfma_f32_16x16x32_bf16(Dh1, bh1, a, 0, 0, 0);
        a = __builtin_amdgcn_mfma_f32_16x16x32_bf16(Dh0, bl0, a, 0, 0, 0);
        a = __builtin_amdgcn_mfma_f32_16x16x32_bf16(Dh1, bl1, a, 0, 0, 0);
        a = __builtin_amdgcn_mfma_f32_16x16x32_bf16(Dl0, bh0, a, 0, 0, 0);
        a = __builtin_amdgcn_mfma_f32_16x16x32_bf16(Dl1, bh1, a, 0, 0, 0);
#pragma unroll
        for (int r4 = 0; r4 < 4; ++r4)
            tld[(quad * 4 + r4) * 68 + nt * 16 + m16] = silu_f(a[r4] + db1v[nt]);
    }
    __syncthreads();
    // ---- decoder layer 2 + mask + pool ----
    float a3[16];
    *(float4*)&a3[0]  = *(const float4*)&tld[m16 * 68 + quad * 8 + 0];
    *(float4*)&a3[4]  = *(const float4*)&tld[m16 * 68 + quad * 8 + 4];
    *(float4*)&a3[8]  = *(const float4*)&tld[m16 * 68 + quad * 8 + 32];
    *(float4*)&a3[12] = *(const float4*)&tld[m16 * 68 + quad * 8 + 36];
    short8 Eh0, Eh1, El0, El1;
#pragma unroll
    for (int j = 0; j < 8; ++j) {
        unsigned short hi, lo;
        splitbf_t(a3[j], hi, lo);     Eh0[j] = (short)hi; El0[j] = (short)lo;
        splitbf_t(a3[8+j], hi, lo);   Eh1[j] = (short)hi; El1[j] = (short)lo;
    }
#pragma unroll
    for (int nt = 0; nt < 4; ++nt) {
        short8 bh0 = *(const short8*)(wD2 + ((nt*2+0) * 64 + lane) * 8);
        short8 bh1 = *(const short8*)(wD2 + ((nt*2+1) * 64 + lane) * 8);
        short8 bl0 = *(const short8*)(wD2 + 4096 + ((nt*2+0) * 64 + lane) * 8);
        short8 bl1 = *(const short8*)(wD2 + 4096 + ((nt*2+1) * 64 + lane) * 8);
        f32x4 a = {0.0f, 0.0f, 0.0f, 0.0f};
        a = __builtin_amdgcn_mfma_f32_16x16x32_bf16(Eh0, bh0, a, 0, 0, 0);
        a = __builtin_amdgcn_mfma_f32_16x16x32_bf16(Eh1, bh1, a, 0, 0, 0);
        a = __builtin_amdgcn_mfma_f32_16x16x32_bf16(Eh0, bl0, a, 0, 0, 0);
        a = __builtin_amdgcn_mfma_f32_16x16x32_bf16(Eh1, bl1, a, 0, 0, 0);
        a = __builtin_amdgcn_mfma_f32_16x16x32_bf16(El0, bh0, a, 0, 0, 0);
        a = __builtin_amdgcn_mfma_f32_16x16x32_bf16(El1, bh1, a, 0, 0, 0);
        float s = 0.0f;
#pragma unroll
        for (int r4 = 0; r4 < 4; ++r4)
            s += (a[r4] + db2v[nt]) * nm[r4];
        s += __shfl_xor(s, 16);
        s += __shfl_xor(s, 32);
        if (quad == 0) hgs[nt * 16 + m16] = s;
    }
    __syncthreads();
    // ---- graph decoder + reaction aggregation ----
    float acc = gb1[lane];
#pragma unroll
    for (int k = 0; k < H; ++k)
        acc += hgs[k] * gW1[k * H + lane];
    float part = silu_f(acc) * gW2[lane];
#pragma unroll
    for (int off = 32; off > 0; off >>= 1)
        part += __shfl_down(part, off);
    if (lane == 0)
        atomAddF(&pred[rid[blockIdx.x]], (part + gb2[0]) * rsign[blockIdx.x]);
}

extern "C" void kernel_launch(void* const* d_in, const int* in_sizes, int n_in,
                              void* d_out, int out_size, void* d_ws, size_t ws_size,
                              hipStream_t stream) {
    const float* h0      = (const float*)d_in[0];
    const float* pos     = (const float*)d_in[1];
    const int*   edges   = (const int*)d_in[2];
    const float* nmask   = (const float*)d_in[3];
    const float* emask   = (const float*)d_in[4];
    const int*   rid     = (const int*)d_in[5];
    const float* rsign   = (const float*)d_in[6];
    const float* emb_w   = (const float*)d_in[7];
    const float* emb_b   = (const float*)d_in[8];
    const float* edge_w1 = (const float*)d_in[9];
    const float* edge_b1 = (const float*)d_in[10];
    const float* edge_w2 = (const float*)d_in[11];
    const float* edge_b2 = (const float*)d_in[12];
    const float* node_w1 = (const float*)d_in[13];
    const float* node_b1 = (const float*)d_in[14];
    const float* node_w2 = (const float*)d_in[15];
    const float* node_b2 = (const float*)d_in[16];
    const float* dec_w1  = (const float*)d_in[17];
    const float* dec_b1  = (const float*)d_in[18];
    const float* dec_w2  = (const float*)d_in[19];
    const float* dec_b2  = (const float*)d_in[20];
    const float* g_w1    = (const float*)d_in[21];
    const float* g_b1    = (const float*)d_in[22];
    const float* g_w2    = (const float*)d_in[23];
    const float* g_b2    = (const float*)d_in[24];

    float* h      = (float*)d_ws;            // N*H
    float* agg    = h + N_NODES * H;         // N*H
    float* PA     = agg + N_NODES * H;       // N*H
    float* PB     = PA + N_NODES * H;        // N*H
    float4* csrQ  = (float4*)(PB + N_NODES * H);   // E float4 (16B aligned)
    int*   deg    = (int*)(csrQ + N_EDGES);  // N
    int*   off    = deg + N_NODES;           // N
    int*   bsum   = off + N_NODES;           // 256
    int*   bbase  = bsum + 256;              // 256
    int*   nstart = bbase + 256;             // N+1
    int*   cursor = nstart + N_NODES + 1;    // N
    short* wsW    = (short*)((((uintptr_t)(cursor + N_NODES)) + 255) & ~(uintptr_t)255);
    float* pred   = (float*)d_out;

    hipMemsetAsync(d_out, 0, R_REACT * sizeof(float), stream);
    hipMemsetAsync(deg, 0, N_NODES * sizeof(int), stream);

    k_prepw<<<228, 64, 0, stream>>>(edge_w1, edge_w2, node_w1, node_w2,
                                    dec_w1, dec_w2, emb_w, wsW);
    k_hist<<<N_EDGES / 256, 256, 0, stream>>>(edges, deg);
    k_scan_blk<<<256, 128, 0, stream>>>(deg, off, bsum);
    k_scan_top<<<1, 256, 0, stream>>>(bsum, bbase);
    k_cursor<<<N_NODES / 256, 256, 0, stream>>>(off, bbase, nstart, cursor);
    k_fill<<<N_EDGES / 256, 256, 0, stream>>>(edges, pos, emask, cursor, csrQ);
    k_embed_proj<<<N_NODES / 16, 64, 0, stream>>>(
        h0, wsW + WEMB, emb_b, wsW + WPROJ, edge_b1, h, PA, PB);

    for (int i = 0; i < L_LAYERS; ++i) {
        k_edge6<<<N_NODES / NPBLK, 256, 0, stream>>>(
            PA, PB, nstart, csrQ,
            edge_w1 + i * EIN * H,
            wsW + WE2 + i * 8192, edge_b2 + i * H, agg);
        if (i < L_LAYERS - 1) {
            k_node_proj<<<N_NODES / 16, 64, 0, stream>>>(
                h, agg, h0,
                wsW + WN1 + i * 20480, node_b1 + i * H,
                wsW + WN2 + i * 8192,  node_b2 + i * H,
                wsW + WPROJ + (i + 1) * 16384, edge_b1 + (i + 1) * H,
                PA, PB);
        } else {
            k_node_dec_graph<<<N_NODES / 16, 64, 0, stream>>>(
                h, agg, h0,
                wsW + WN1 + i * 20480, node_b1 + i * H,
                wsW + WN2 + i * 8192,  node_b2 + i * H,
                wsW + WD1, dec_b1, wsW + WD2, dec_b2,
                nmask, g_w1, g_b1, g_w2, g_b2, rid, rsign, pred);
        }
    }
}